// Round 1
// baseline (19335.732 us; speedup 1.0000x reference)
//
#include <hip/hip_runtime.h>

// ---------------------------------------------------------------------------
// MashDecoder forward, fp32, correctness-first round.
// B=4, NA=400 (L), NQ=4096, D_HIDDEN=400, D_INNER=800, D_STATE=16, DT_RANK=25
// ---------------------------------------------------------------------------

#define EPI_NONE 0
#define EPI_SOFTPLUS 1
#define EPI_GEGLU 2

static __device__ __forceinline__ float silu_f(float x) {
  return x / (1.f + __expf(-x));
}
static __device__ __forceinline__ float softplus_f(float x) {
  return fmaxf(x, 0.f) + log1pf(__expf(-fabsf(x)));
}
static __device__ __forceinline__ float gelu_f(float x) {
  const float c = 0.7978845608028654f;  // sqrt(2/pi)
  return 0.5f * x * (1.f + tanhf(c * (x + 0.044715f * x * x * x)));
}

// ---------------------------------------------------------------------------
// Generic GEMM: C[M,N] = epi(A[M,K] @ W[N,K]^T + bias) (+ aux as residual,
// or aux as GEGLU 'a' operand). 256 threads, (BM/TM)*(BN/TN)==256, BM*BK==1024.
// ---------------------------------------------------------------------------
template <int BM, int BN, int BK, int TM, int TN, int EPI>
__global__ __launch_bounds__(256) void gemm_k(
    const float* __restrict__ A, int lda,
    const float* __restrict__ W, int ldw,
    const float* __restrict__ bias,
    const float* __restrict__ aux, int ldaux,
    float* __restrict__ C, int ldc,
    int M, int N, int K) {
  __shared__ float As[BK][BM];
  __shared__ float Bs[BK][BN];
  const int tid = threadIdx.x;
  const int tx = tid % (BN / TN);
  const int ty = tid / (BN / TN);
  const int m0 = blockIdx.y * BM;
  const int n0 = blockIdx.x * BN;

  float acc[TM][TN];
#pragma unroll
  for (int i = 0; i < TM; ++i)
#pragma unroll
    for (int j = 0; j < TN; ++j) acc[i][j] = 0.f;

  const int a_row = (tid * 4) / BK;
  const int a_col = (tid * 4) % BK;

  for (int k0 = 0; k0 < K; k0 += BK) {
    // stage A tile (transposed to [BK][BM])
    {
      int gm = m0 + a_row, gk = k0 + a_col;
      float4 v = make_float4(0.f, 0.f, 0.f, 0.f);
      if (gm < M) {
        if (gk + 3 < K) {
          v = *reinterpret_cast<const float4*>(A + (size_t)gm * lda + gk);
        } else {
          float tmp[4];
#pragma unroll
          for (int q = 0; q < 4; ++q)
            tmp[q] = (gk + q < K) ? A[(size_t)gm * lda + gk + q] : 0.f;
          v = make_float4(tmp[0], tmp[1], tmp[2], tmp[3]);
        }
      }
      As[a_col + 0][a_row] = v.x;
      As[a_col + 1][a_row] = v.y;
      As[a_col + 2][a_row] = v.z;
      As[a_col + 3][a_row] = v.w;
    }
    // stage W tile (transposed to [BK][BN])
    {
      int gn = n0 + a_row, gk = k0 + a_col;
      float4 v = make_float4(0.f, 0.f, 0.f, 0.f);
      if (gn < N) {
        if (gk + 3 < K) {
          v = *reinterpret_cast<const float4*>(W + (size_t)gn * ldw + gk);
        } else {
          float tmp[4];
#pragma unroll
          for (int q = 0; q < 4; ++q)
            tmp[q] = (gk + q < K) ? W[(size_t)gn * ldw + gk + q] : 0.f;
          v = make_float4(tmp[0], tmp[1], tmp[2], tmp[3]);
        }
      }
      Bs[a_col + 0][a_row] = v.x;
      Bs[a_col + 1][a_row] = v.y;
      Bs[a_col + 2][a_row] = v.z;
      Bs[a_col + 3][a_row] = v.w;
    }
    __syncthreads();
#pragma unroll
    for (int kk = 0; kk < BK; ++kk) {
      float a[TM], bb[TN];
#pragma unroll
      for (int i = 0; i < TM; i += 4)
        *reinterpret_cast<float4*>(&a[i]) =
            *reinterpret_cast<const float4*>(&As[kk][ty * TM + i]);
#pragma unroll
      for (int j = 0; j < TN; j += 4)
        *reinterpret_cast<float4*>(&bb[j]) =
            *reinterpret_cast<const float4*>(&Bs[kk][tx * TN + j]);
#pragma unroll
      for (int i = 0; i < TM; ++i)
#pragma unroll
        for (int j = 0; j < TN; ++j) acc[i][j] = fmaf(a[i], bb[j], acc[i][j]);
    }
    __syncthreads();
  }

#pragma unroll
  for (int i = 0; i < TM; ++i) {
    int m = m0 + ty * TM + i;
    if (m >= M) continue;
#pragma unroll
    for (int j = 0; j < TN; ++j) {
      int n = n0 + tx * TN + j;
      if (n >= N) continue;
      float v = acc[i][j];
      if (bias) v += bias[n];
      if (EPI == EPI_SOFTPLUS) {
        v = softplus_f(v);
      } else if (EPI == EPI_GEGLU) {
        v = aux[(size_t)m * ldaux + n] * gelu_f(v);
      } else if (aux) {
        v += aux[(size_t)m * ldaux + n];
      }
      C[(size_t)m * ldc + n] = v;
    }
  }
}

// ---------------------------------------------------------------------------
// Point embeds
// ---------------------------------------------------------------------------
__global__ void anchor_embed_kernel(const float* __restrict__ mash,
                                    float* __restrict__ aemb) {
  int row = blockIdx.x;  // 0..1599
  int lane = threadIdx.x;
  if (lane >= 54) return;
  const float PI = 3.14159265358979323846f;
  float e;
  if (lane < 48) {
    int j = (lane < 24) ? lane : lane - 24;
    int d = j >> 2, f = j & 3;  // nf = 4
    float v = mash[row * 31 + d] * (PI * (float)(1 << f));
    e = (lane < 24) ? sinf(v) : cosf(v);
  } else {
    e = mash[row * 31 + (lane - 48)];
  }
  aemb[row * 54 + lane] = e;
}

__global__ void point_embed_q_kernel(const float* __restrict__ qry,
                                     float* __restrict__ qep) {
  int row = blockIdx.x;  // 0..16383
  int lane = threadIdx.x;
  if (lane >= 51) return;
  const float PI = 3.14159265358979323846f;
  float e;
  if (lane < 48) {
    int j = (lane < 24) ? lane : lane - 24;
    int d = j >> 3, f = j & 7;  // nf = 8
    float v = qry[row * 3 + d] * (PI * (float)(1 << f));
    e = (lane < 24) ? sinf(v) : cosf(v);
  } else {
    e = qry[row * 3 + (lane - 48)];
  }
  qep[row * 51 + lane] = e;
}

__global__ void copy_tail_kernel(const float* __restrict__ mash,
                                 float* __restrict__ x) {
  int idx = blockIdx.x * 256 + threadIdx.x;
  if (idx >= 1600 * 25) return;
  int row = idx / 25, j = idx % 25;
  x[row * 400 + 375 + j] = mash[row * 31 + 6 + j];
}

// ---------------------------------------------------------------------------
// Norms (one 64-lane wave per 400-wide row)
// ---------------------------------------------------------------------------
__global__ void rmsnorm_kernel(const float* __restrict__ x,
                               const float* __restrict__ w,
                               float* __restrict__ out) {
  int row = blockIdx.x;
  int lane = threadIdx.x;
  float ss = 0.f;
  float vals[7];
  int nv = 0;
  for (int c = lane; c < 400; c += 64) {
    float v = x[(size_t)row * 400 + c];
    vals[nv++] = v;
    ss += v * v;
  }
#pragma unroll
  for (int off = 1; off < 64; off <<= 1) ss += __shfl_xor(ss, off);
  float r = rsqrtf(ss * (1.f / 400.f) + 1e-5f);
  nv = 0;
  for (int c = lane; c < 400; c += 64) out[(size_t)row * 400 + c] = vals[nv++] * r * w[c];
}

__global__ void layernorm_kernel(const float* __restrict__ x,
                                 const float* __restrict__ w,
                                 const float* __restrict__ b,
                                 float* __restrict__ out) {
  int row = blockIdx.x;
  int lane = threadIdx.x;
  float s = 0.f, s2 = 0.f;
  float vals[7];
  int nv = 0;
  for (int c = lane; c < 400; c += 64) {
    float v = x[(size_t)row * 400 + c];
    vals[nv++] = v;
    s += v;
    s2 += v * v;
  }
#pragma unroll
  for (int off = 1; off < 64; off <<= 1) {
    s += __shfl_xor(s, off);
    s2 += __shfl_xor(s2, off);
  }
  float mu = s * (1.f / 400.f);
  float var = s2 * (1.f / 400.f) - mu * mu;
  float r = rsqrtf(var + 1e-5f);
  nv = 0;
  for (int c = lane; c < 400; c += 64)
    out[(size_t)row * 400 + c] = (vals[nv++] - mu) * r * w[c] + b[c];
}

// ---------------------------------------------------------------------------
// Mamba pieces
// ---------------------------------------------------------------------------
__global__ void conv_silu_kernel(const float* __restrict__ uz,
                                 const float* __restrict__ cw,
                                 const float* __restrict__ cb,
                                 float* __restrict__ uc) {
  int idx = blockIdx.x * 256 + threadIdx.x;
  if (idx >= 1600 * 800) return;
  int c = idx % 800;
  int row = idx / 800;
  int l = row % 400;
  int b = row / 400;
  float acc = cb[c];
  float w0 = cw[c * 4 + 0], w1 = cw[c * 4 + 1], w2 = cw[c * 4 + 2], w3 = cw[c * 4 + 3];
  const float* ub = uz + (size_t)b * 400 * 1600 + c;
  if (l >= 3) acc += ub[(size_t)(l - 3) * 1600] * w0;
  if (l >= 2) acc += ub[(size_t)(l - 2) * 1600] * w1;
  if (l >= 1) acc += ub[(size_t)(l - 1) * 1600] * w2;
  acc += ub[(size_t)l * 1600] * w3;
  uc[idx] = silu_f(acc);
}

// 4 lanes per (b,d) channel, each owning 4 of the 16 states.
__global__ void scan_kernel(const float* __restrict__ uc,
                            const float* __restrict__ dt,
                            const float* __restrict__ dbc,
                            const float* __restrict__ A_log,
                            const float* __restrict__ Dp,
                            float* __restrict__ y) {
  int t = blockIdx.x * 256 + threadIdx.x;
  if (t >= 12800) return;
  int g = t & 3;
  int bd = t >> 2;
  int b = bd / 800;
  int d = bd - b * 800;
  float A0 = -__expf(A_log[d * 16 + g * 4 + 0]);
  float A1 = -__expf(A_log[d * 16 + g * 4 + 1]);
  float A2 = -__expf(A_log[d * 16 + g * 4 + 2]);
  float A3 = -__expf(A_log[d * 16 + g * 4 + 3]);
  float Dpd = Dp[d];
  float h0 = 0.f, h1 = 0.f, h2 = 0.f, h3 = 0.f;
  const int off = 25 + g * 4;
  for (int l = 0; l < 400; ++l) {
    size_t base = (size_t)(b * 400 + l);
    float dtv = dt[base * 800 + d];
    float uv = uc[base * 800 + d];
    float du = dtv * uv;
    const float* bc = dbc + base * 57;
    float B0 = bc[off + 0], B1 = bc[off + 1], B2 = bc[off + 2], B3 = bc[off + 3];
    float C0 = bc[off + 16], C1 = bc[off + 17], C2 = bc[off + 18], C3 = bc[off + 19];
    h0 = __expf(dtv * A0) * h0 + du * B0;
    h1 = __expf(dtv * A1) * h1 + du * B1;
    h2 = __expf(dtv * A2) * h2 + du * B2;
    h3 = __expf(dtv * A3) * h3 + du * B3;
    float yv = h0 * C0 + h1 * C1 + h2 * C2 + h3 * C3;
    yv += __shfl_xor(yv, 1);
    yv += __shfl_xor(yv, 2);
    if (g == 0) y[base * 800 + d] = yv + uv * Dpd;
  }
}

__global__ void gate_kernel(const float* __restrict__ y,
                            const float* __restrict__ uz,
                            float* __restrict__ gbuf) {
  int idx = blockIdx.x * 256 + threadIdx.x;
  if (idx >= 1600 * 800) return;
  int row = idx / 800, c = idx % 800;
  float z = uz[(size_t)row * 1600 + 800 + c];
  gbuf[idx] = y[idx] * silu_f(z);
}

// ---------------------------------------------------------------------------
// Cross-attention: one block = 32 q-rows for one (b,h). na=400, d=400.
// ---------------------------------------------------------------------------
__global__ __launch_bounds__(256) void attn_kernel(const float* __restrict__ qh,
                                                   const float* __restrict__ kv,
                                                   float* __restrict__ oh, int h) {
  __shared__ float qs[32][400];
  __shared__ float ss[32][400];
  __shared__ float ks[400][8];
  __shared__ float ls[32];
  const int tid = threadIdx.x;
  const int b = blockIdx.y;
  const int row0 = b * 4096 + blockIdx.x * 32;

  for (int idx = tid; idx < 32 * 400; idx += 256) {
    int r = idx / 400, c = idx % 400;
    qs[r][c] = qh[(size_t)(row0 + r) * 400 + c];
  }
  __syncthreads();

  const int tx = tid & 15, ty = tid >> 4;
  const int r0 = ty * 2, r1 = ty * 2 + 1;

  float s0[25], s1[25];
#pragma unroll
  for (int ci = 0; ci < 25; ++ci) { s0[ci] = 0.f; s1[ci] = 0.f; }

  // Phase A: scores = q @ k^T
  for (int k0 = 0; k0 < 400; k0 += 8) {
    for (int idx = tid; idx < 400 * 8; idx += 256) {
      int j = idx >> 3, c = idx & 7;
      ks[j][c] = kv[(size_t)(b * 400 + j) * 6400 + h * 400 + k0 + c];
    }
    __syncthreads();
#pragma unroll
    for (int kq = 0; kq < 8; kq += 4) {
      float4 qa0 = *reinterpret_cast<const float4*>(&qs[r0][k0 + kq]);
      float4 qa1 = *reinterpret_cast<const float4*>(&qs[r1][k0 + kq]);
#pragma unroll
      for (int ci = 0; ci < 25; ++ci) {
        float4 kb = *reinterpret_cast<const float4*>(&ks[tx + 16 * ci][kq]);
        s0[ci] += qa0.x * kb.x + qa0.y * kb.y + qa0.z * kb.z + qa0.w * kb.w;
        s1[ci] += qa1.x * kb.x + qa1.y * kb.y + qa1.z * kb.z + qa1.w * kb.w;
      }
    }
    __syncthreads();
  }

  // softmax over 400 keys (16-lane groups own a row pair)
  const float scale = 0.05f;  // 400^-0.5
  float m0v = -1e30f, m1v = -1e30f;
#pragma unroll
  for (int ci = 0; ci < 25; ++ci) {
    m0v = fmaxf(m0v, s0[ci]);
    m1v = fmaxf(m1v, s1[ci]);
  }
#pragma unroll
  for (int off = 1; off < 16; off <<= 1) {
    m0v = fmaxf(m0v, __shfl_xor(m0v, off));
    m1v = fmaxf(m1v, __shfl_xor(m1v, off));
  }
  float l0 = 0.f, l1 = 0.f;
#pragma unroll
  for (int ci = 0; ci < 25; ++ci) {
    float p0 = __expf(scale * (s0[ci] - m0v));
    float p1 = __expf(scale * (s1[ci] - m1v));
    s0[ci] = p0;
    s1[ci] = p1;
    l0 += p0;
    l1 += p1;
  }
#pragma unroll
  for (int off = 1; off < 16; off <<= 1) {
    l0 += __shfl_xor(l0, off);
    l1 += __shfl_xor(l1, off);
  }
#pragma unroll
  for (int ci = 0; ci < 25; ++ci) {
    ss[r0][tx + 16 * ci] = s0[ci];
    ss[r1][tx + 16 * ci] = s1[ci];
  }
  if (tx == 0) {
    ls[r0] = 1.f / l0;
    ls[r1] = 1.f / l1;
  }

  // Phase B: out = P @ V
  float o0[25], o1[25];
#pragma unroll
  for (int ci = 0; ci < 25; ++ci) { o0[ci] = 0.f; o1[ci] = 0.f; }

  float* vs = &ks[0][0];  // reuse as [8][400]
  for (int j0 = 0; j0 < 400; j0 += 8) {
    __syncthreads();
    for (int idx = tid; idx < 8 * 400; idx += 256) {
      int j = idx / 400, c = idx % 400;
      vs[j * 400 + c] = kv[(size_t)(b * 400 + j0 + j) * 6400 + 3200 + h * 400 + c];
    }
    __syncthreads();
    float p0[8], p1[8];
    *reinterpret_cast<float4*>(&p0[0]) = *reinterpret_cast<const float4*>(&ss[r0][j0]);
    *reinterpret_cast<float4*>(&p0[4]) = *reinterpret_cast<const float4*>(&ss[r0][j0 + 4]);
    *reinterpret_cast<float4*>(&p1[0]) = *reinterpret_cast<const float4*>(&ss[r1][j0]);
    *reinterpret_cast<float4*>(&p1[4]) = *reinterpret_cast<const float4*>(&ss[r1][j0 + 4]);
#pragma unroll
    for (int j = 0; j < 8; ++j) {
#pragma unroll
      for (int ci = 0; ci < 25; ++ci) {
        float v = vs[j * 400 + tx + 16 * ci];
        o0[ci] = fmaf(p0[j], v, o0[ci]);
        o1[ci] = fmaf(p1[j], v, o1[ci]);
      }
    }
  }
  __syncthreads();
#pragma unroll
  for (int ci = 0; ci < 25; ++ci) {
    ss[r0][tx + 16 * ci] = o0[ci];
    ss[r1][tx + 16 * ci] = o1[ci];
  }
  __syncthreads();
  for (int idx = tid; idx < 32 * 400; idx += 256) {
    int r = idx / 400, c = idx % 400;
    oh[(size_t)(row0 + r) * 400 + c] = ss[r][c] * ls[r];
  }
}

// ---------------------------------------------------------------------------
// misc
// ---------------------------------------------------------------------------
__global__ void bias_init_kernel(const float* __restrict__ bias,
                                 float* __restrict__ out) {
  int idx = blockIdx.x * 256 + threadIdx.x;
  if (idx < 16384 * 400) out[idx] = bias[idx % 400];
}

__global__ void head_kernel(const float* __restrict__ lat,
                            const float* __restrict__ hw,
                            const float* __restrict__ hb,
                            float* __restrict__ out) {
  int row = blockIdx.x * 4 + (threadIdx.x >> 6);
  int lane = threadIdx.x & 63;
  float s = 0.f;
  for (int c = lane; c < 400; c += 64) s += lat[(size_t)row * 400 + c] * hw[c];
#pragma unroll
  for (int off = 1; off < 64; off <<= 1) s += __shfl_xor(s, off);
  if (lane == 0) out[row] = s + hb[0];
}

// ---------------------------------------------------------------------------
// host
// ---------------------------------------------------------------------------
static inline int cdiv(int a, int b) { return (a + b - 1) / b; }

extern "C" void kernel_launch(void* const* d_in, const int* in_sizes, int n_in,
                              void* d_out, int out_size, void* d_ws, size_t ws_size,
                              hipStream_t stream) {
  (void)in_sizes; (void)n_in; (void)out_size;

  const float* mash     = (const float*)d_in[0];
  const float* qry      = (const float*)d_in[1];
  const float* anchor_w = (const float*)d_in[2];
  const float* anchor_b = (const float*)d_in[3];
  const float* point_w  = (const float*)d_in[4];
  const float* point_b  = (const float*)d_in[5];
  const float* norm_w   = (const float*)d_in[6];
  const float* in_w     = (const float*)d_in[7];
  const float* conv_w   = (const float*)d_in[8];
  const float* conv_b   = (const float*)d_in[9];
  const float* xproj_w  = (const float*)d_in[10];
  const float* dt_w     = (const float*)d_in[11];
  const float* dt_b     = (const float*)d_in[12];
  const float* A_log    = (const float*)d_in[13];
  const float* Dp       = (const float*)d_in[14];
  const float* out_w    = (const float*)d_in[15];
  const float* ln_q_w   = (const float*)d_in[16];
  const float* ln_q_b   = (const float*)d_in[17];
  const float* ln_c_w   = (const float*)d_in[18];
  const float* ln_c_b   = (const float*)d_in[19];
  const float* to_q_w   = (const float*)d_in[20];
  const float* to_kv_w  = (const float*)d_in[21];
  const float* to_out_w = (const float*)d_in[22];
  const float* to_out_b = (const float*)d_in[23];
  const float* ff_ln_w  = (const float*)d_in[24];
  const float* ff_ln_b  = (const float*)d_in[25];
  const float* ff_w1    = (const float*)d_in[26];
  const float* ff_b1    = (const float*)d_in[27];
  const float* ff_w2    = (const float*)d_in[28];
  const float* ff_b2    = (const float*)d_in[29];
  const float* head_w   = (const float*)d_in[30];
  const float* head_b   = (const float*)d_in[31];

  // workspace layout (floats)
  const size_t OFF_X    = 0;                      // 640,000
  const size_t OFF_XN   = 640000;                 // 640,000 (reused as ctx)
  const size_t OFF_POOL = 1280000;                // 10,240,000 total pool
  const size_t OFF_UZ   = OFF_POOL;               // 2,560,000
  const size_t OFF_UC   = OFF_POOL + 2560000;     // 1,280,000
  const size_t OFF_DT   = OFF_POOL + 3840000;     // 1,280,000
  const size_t OFF_Y    = OFF_POOL + 5120000;     // 1,280,000
  const size_t OFF_GATE = OFF_POOL + 6400000;     // 1,280,000
  const size_t OFF_DBC  = OFF_POOL + 7680000;     //    91,200
  const size_t OFF_AEMB = OFF_POOL + 7780000;     //    86,400
  const size_t OFF_KV   = OFF_POOL;               // 10,240,000 (attn phase)
  const size_t OFF_QEMB = 11520000;               // 6,553,600 (reused: latents)
  const size_t OFF_QN   = 18073600;               // 6,553,600
  const size_t OFF_QEP  = 24627200;               // 6,553,600 (qep / qh / lnl)
  const size_t OFF_OH   = 31180800;               // 6,553,600 (oh / ffa)
  const size_t OFF_FFG  = 37734400;               // 6,553,600
  const size_t TOTAL    = 44288000;

  if (ws_size < TOTAL * sizeof(float)) return;  // workspace too small

  float* ws   = (float*)d_ws;
  float* X    = ws + OFF_X;
  float* XN   = ws + OFF_XN;   // also ctx
  float* UZ   = ws + OFF_UZ;
  float* UC   = ws + OFF_UC;
  float* DTB  = ws + OFF_DT;
  float* YB   = ws + OFF_Y;
  float* GB   = ws + OFF_GATE;
  float* DBC  = ws + OFF_DBC;
  float* AEMB = ws + OFF_AEMB;
  float* KV   = ws + OFF_KV;
  float* QEMB = ws + OFF_QEMB;
  float* LAT  = ws + OFF_QEMB;  // reuses qemb slot after qn is computed
  float* QN   = ws + OFF_QN;
  float* QEP  = ws + OFF_QEP;
  float* QH   = ws + OFF_QEP;
  float* LNL  = ws + OFF_QEP;
  float* OH   = ws + OFF_OH;
  float* FFA  = ws + OFF_OH;
  float* FFG  = ws + OFF_FFG;

  // ---- anchor embed -> x [1600,400] ----
  anchor_embed_kernel<<<1600, 64, 0, stream>>>(mash, AEMB);
  gemm_k<64, 64, 16, 4, 4, EPI_NONE><<<dim3(cdiv(375, 64), cdiv(1600, 64)), 256, 0, stream>>>(
      AEMB, 54, anchor_w, 54, anchor_b, nullptr, 0, X, 400, 1600, 375, 54);
  copy_tail_kernel<<<cdiv(1600 * 25, 256), 256, 0, stream>>>(mash, X);

  // ---- 24 mamba blocks ----
  for (int L = 0; L < 24; ++L) {
    rmsnorm_kernel<<<1600, 64, 0, stream>>>(X, norm_w + (size_t)L * 400, XN);
    gemm_k<64, 64, 16, 4, 4, EPI_NONE><<<dim3(25, 25), 256, 0, stream>>>(
        XN, 400, in_w + (size_t)L * 1600 * 400, 400, nullptr, nullptr, 0, UZ, 1600,
        1600, 1600, 400);
    conv_silu_kernel<<<cdiv(1600 * 800, 256), 256, 0, stream>>>(
        UZ, conv_w + (size_t)L * 3200, conv_b + (size_t)L * 800, UC);
    gemm_k<64, 64, 16, 4, 4, EPI_NONE><<<dim3(1, 25), 256, 0, stream>>>(
        UC, 800, xproj_w + (size_t)L * 57 * 800, 800, nullptr, nullptr, 0, DBC, 57,
        1600, 57, 800);
    gemm_k<64, 64, 16, 4, 4, EPI_SOFTPLUS><<<dim3(13, 25), 256, 0, stream>>>(
        DBC, 57, dt_w + (size_t)L * 800 * 25, 25, dt_b + (size_t)L * 800, nullptr, 0,
        DTB, 800, 1600, 800, 25);
    scan_kernel<<<50, 256, 0, stream>>>(UC, DTB, DBC, A_log + (size_t)L * 12800,
                                        Dp + (size_t)L * 800, YB);
    gate_kernel<<<cdiv(1600 * 800, 256), 256, 0, stream>>>(YB, UZ, GB);
    gemm_k<64, 64, 16, 4, 4, EPI_NONE><<<dim3(cdiv(400, 64), 25), 256, 0, stream>>>(
        GB, 800, out_w + (size_t)L * 400 * 800, 800, nullptr, X, 400, X, 400, 1600,
        400, 800);
  }

  // ---- context: LN + KV projection ----
  layernorm_kernel<<<1600, 64, 0, stream>>>(X, ln_c_w, ln_c_b, XN);  // XN = ctx
  gemm_k<128, 128, 8, 8, 8, EPI_NONE><<<dim3(50, 13), 256, 0, stream>>>(
      XN, 400, to_kv_w, 400, nullptr, nullptr, 0, KV, 6400, 1600, 6400, 400);

  // ---- query embed + LN ----
  point_embed_q_kernel<<<16384, 64, 0, stream>>>(qry, QEP);
  gemm_k<128, 128, 8, 8, 8, EPI_NONE><<<dim3(cdiv(400, 128), 128), 256, 0, stream>>>(
      QEP, 51, point_w, 51, point_b, nullptr, 0, QEMB, 400, 16384, 400, 51);
  layernorm_kernel<<<16384, 64, 0, stream>>>(QEMB, ln_q_w, ln_q_b, QN);

  // ---- attention, per head, accumulate into latents ----
  bias_init_kernel<<<cdiv(16384 * 400, 256), 256, 0, stream>>>(to_out_b, LAT);
  for (int h = 0; h < 8; ++h) {
    gemm_k<128, 128, 8, 8, 8, EPI_NONE><<<dim3(cdiv(400, 128), 128), 256, 0, stream>>>(
        QN, 400, to_q_w + (size_t)h * 400 * 400, 400, nullptr, nullptr, 0, QH, 400,
        16384, 400, 400);
    attn_kernel<<<dim3(128, 4), 256, 0, stream>>>(QH, KV, OH, h);
    gemm_k<128, 128, 8, 8, 8, EPI_NONE><<<dim3(cdiv(400, 128), 128), 256, 0, stream>>>(
        OH, 400, to_out_w + (size_t)h * 400, 3200, nullptr, LAT, 400, LAT, 400, 16384,
        400, 400);
  }

  // ---- GEGLU FF (chunked per batch to bound scratch) ----
  layernorm_kernel<<<16384, 64, 0, stream>>>(LAT, ff_ln_w, ff_ln_b, LNL);
  for (int bb = 0; bb < 4; ++bb) {
    const float* lnb = LNL + (size_t)bb * 4096 * 400;
    float* latb = LAT + (size_t)bb * 4096 * 400;
    gemm_k<128, 128, 8, 8, 8, EPI_NONE><<<dim3(cdiv(1600, 128), 32), 256, 0, stream>>>(
        lnb, 400, ff_w1, 400, ff_b1, nullptr, 0, FFA, 1600, 4096, 1600, 400);
    gemm_k<128, 128, 8, 8, 8, EPI_GEGLU><<<dim3(cdiv(1600, 128), 32), 256, 0, stream>>>(
        lnb, 400, ff_w1 + (size_t)1600 * 400, 400, ff_b1 + 1600, FFA, 1600, FFG, 1600,
        4096, 1600, 400);
    gemm_k<64, 64, 16, 4, 4, EPI_NONE><<<dim3(cdiv(400, 64), 64), 256, 0, stream>>>(
        FFG, 1600, ff_w2, 1600, ff_b2, latb, 400, latb, 400, 4096, 400, 1600);
  }

  // ---- head ----
  head_kernel<<<4096, 256, 0, stream>>>(LAT, head_w, head_b, (float*)d_out);
}

// Round 2
// 15345.737 us; speedup vs baseline: 1.2600x; 1.2600x over previous
//
#include <hip/hip_runtime.h>

// ---------------------------------------------------------------------------
// MashDecoder forward. Round 2: bf16 MFMA for all large GEMMs.
// B=4, NA=400, NQ=4096, D_HIDDEN=400, D_INNER=800, D_STATE=16, DT_RANK=25
// ---------------------------------------------------------------------------

#define EPI_NONE 0
#define EPI_SOFTPLUS 1
#define EPI_RES 2
#define EPI_GEGLU 3

typedef short bf16x8 __attribute__((ext_vector_type(8)));
typedef float f32x4 __attribute__((ext_vector_type(4)));

static __device__ __forceinline__ float silu_f(float x) {
  return x / (1.f + __expf(-x));
}
static __device__ __forceinline__ float softplus_f(float x) {
  return fmaxf(x, 0.f) + log1pf(__expf(-fabsf(x)));
}
static __device__ __forceinline__ float gelu_f(float x) {
  const float c = 0.7978845608028654f;  // sqrt(2/pi)
  return 0.5f * x * (1.f + tanhf(c * (x + 0.044715f * x * x * x)));
}
static __device__ __forceinline__ unsigned short f2bf(float f) {
  union { float f; unsigned int u; } v; v.f = f;
  unsigned int r = v.u + 0x7FFFu + ((v.u >> 16) & 1u);  // RNE
  return (unsigned short)(r >> 16);
}
static __device__ __forceinline__ float bf2f(unsigned short h) {
  union { unsigned int u; float f; } v; v.u = ((unsigned int)h) << 16;
  return v.f;
}

// ---------------------------------------------------------------------------
// Weight convert + pad: src fp32 [L][R][C] -> dst bf16 [L][Rp][Cp], zero pad.
// Each thread handles 8 consecutive Cp elements (Cp % 8 == 0).
// ---------------------------------------------------------------------------
__global__ void cvt_w_kernel(const float* __restrict__ src, unsigned short* __restrict__ dst,
                             int Lr, int R, int C, int Rp, int Cp) {
  size_t i8 = ((size_t)blockIdx.x * 256 + threadIdx.x) * 8;
  size_t total = (size_t)Lr * Rp * Cp;
  if (i8 >= total) return;
  int cp = (int)(i8 % Cp);
  size_t rl = i8 / Cp;
  int r = (int)(rl % Rp);
  int l = (int)(rl / Rp);
  const float* s = src + ((size_t)l * R + r) * C + cp;
  bf16x8 o;
#pragma unroll
  for (int q = 0; q < 8; ++q) {
    float v = (r < R && (cp + q) < C) ? s[q] : 0.f;
    o[q] = (short)f2bf(v);
  }
  *reinterpret_cast<bf16x8*>(dst + i8) = o;
}

// ---------------------------------------------------------------------------
// bf16 MFMA GEMM: C[M,N] = epi(A[M,K] @ W[N,K]^T + bias).
// A, W bf16 row-major, K-contiguous, lda/ldw >= K, K % 32 == 0.
// Buffers must be padded so rows [tile*128) are readable (garbage ok).
// 128x128 tile, BK=32, 256 threads (4 waves, 2x2), 16x16x32 MFMA.
// ---------------------------------------------------------------------------
template <int EPI, int OUTBF>
__global__ __launch_bounds__(256) void gemm_bf16_k(
    const unsigned short* __restrict__ A, int lda,
    const unsigned short* __restrict__ W, int ldw,
    const float* __restrict__ bias,
    const float* __restrict__ aux, int ldaux,
    void* __restrict__ Cout, int ldc,
    int M, int N, int K) {
  __shared__ unsigned short As[128 * 32];
  __shared__ unsigned short Bs[128 * 32];
  const int tid = threadIdx.x;
  const int lane = tid & 63;
  const int wid = tid >> 6;
  const int wr = wid >> 1, wc = wid & 1;
  const int m0 = blockIdx.y * 128, n0 = blockIdx.x * 128;

  f32x4 acc[4][4];
#pragma unroll
  for (int i = 0; i < 4; ++i)
#pragma unroll
    for (int j = 0; j < 4; ++j) acc[i][j] = (f32x4){0.f, 0.f, 0.f, 0.f};

  const int i0 = tid;        // 16B chunk id 0..255
  const int i1 = tid + 256;  // 256..511
  const unsigned short* gA0 = A + (size_t)(m0 + (i0 >> 2)) * lda + ((i0 & 3) << 3);
  const unsigned short* gA1 = A + (size_t)(m0 + (i1 >> 2)) * lda + ((i1 & 3) << 3);
  const unsigned short* gB0 = W + (size_t)(n0 + (i0 >> 2)) * ldw + ((i0 & 3) << 3);
  const unsigned short* gB1 = W + (size_t)(n0 + (i1 >> 2)) * ldw + ((i1 & 3) << 3);
  unsigned short* lA0 = &As[i0 * 8];
  unsigned short* lA1 = &As[i1 * 8];
  unsigned short* lB0 = &Bs[i0 * 8];
  unsigned short* lB1 = &Bs[i1 * 8];

  const int fr = lane & 15, fq = lane >> 4;
  const int arow = wr * 64 + fr;
  const int brow = wc * 64 + fr;

  for (int k0 = 0; k0 < K; k0 += 32) {
    __builtin_amdgcn_global_load_lds(
        (const __attribute__((address_space(1))) unsigned int*)(gA0 + k0),
        (__attribute__((address_space(3))) unsigned int*)lA0, 16, 0, 0);
    __builtin_amdgcn_global_load_lds(
        (const __attribute__((address_space(1))) unsigned int*)(gA1 + k0),
        (__attribute__((address_space(3))) unsigned int*)lA1, 16, 0, 0);
    __builtin_amdgcn_global_load_lds(
        (const __attribute__((address_space(1))) unsigned int*)(gB0 + k0),
        (__attribute__((address_space(3))) unsigned int*)lB0, 16, 0, 0);
    __builtin_amdgcn_global_load_lds(
        (const __attribute__((address_space(1))) unsigned int*)(gB1 + k0),
        (__attribute__((address_space(3))) unsigned int*)lB1, 16, 0, 0);
    __syncthreads();
    bf16x8 av[4], bv[4];
#pragma unroll
    for (int mi = 0; mi < 4; ++mi)
      av[mi] = *reinterpret_cast<const bf16x8*>(&As[(arow + mi * 16) * 32 + fq * 8]);
#pragma unroll
    for (int ni = 0; ni < 4; ++ni)
      bv[ni] = *reinterpret_cast<const bf16x8*>(&Bs[(brow + ni * 16) * 32 + fq * 8]);
#pragma unroll
    for (int mi = 0; mi < 4; ++mi)
#pragma unroll
      for (int ni = 0; ni < 4; ++ni)
        acc[mi][ni] =
            __builtin_amdgcn_mfma_f32_16x16x32_bf16(av[mi], bv[ni], acc[mi][ni], 0, 0, 0);
    __syncthreads();
  }

#pragma unroll
  for (int mi = 0; mi < 4; ++mi) {
#pragma unroll
    for (int r = 0; r < 4; ++r) {
      int m = m0 + wr * 64 + mi * 16 + fq * 4 + r;
      if (m >= M) continue;
#pragma unroll
      for (int ni = 0; ni < 4; ++ni) {
        int n = n0 + wc * 64 + ni * 16 + fr;
        if (n >= N) continue;
        float v = acc[mi][ni][r];
        if (bias) v += bias[n];
        if (EPI == EPI_GEGLU) v = aux[(size_t)m * ldaux + n] * gelu_f(v);
        else if (EPI == EPI_RES) v += aux[(size_t)m * ldaux + n];
        if (OUTBF) ((unsigned short*)Cout)[(size_t)m * ldc + n] = f2bf(v);
        else ((float*)Cout)[(size_t)m * ldc + n] = v;
      }
    }
  }
}

// ---------------------------------------------------------------------------
// fp32 GEMM (kept for tiny shapes: anchor embed K=54, dt-proj K=25)
// ---------------------------------------------------------------------------
template <int BM, int BN, int BK, int TM, int TN, int EPI>
__global__ __launch_bounds__(256) void gemm_k(
    const float* __restrict__ A, int lda,
    const float* __restrict__ W, int ldw,
    const float* __restrict__ bias,
    const float* __restrict__ aux, int ldaux,
    float* __restrict__ C, int ldc,
    int M, int N, int K) {
  __shared__ float As[BK][BM];
  __shared__ float Bs[BK][BN];
  const int tid = threadIdx.x;
  const int tx = tid % (BN / TN);
  const int ty = tid / (BN / TN);
  const int m0 = blockIdx.y * BM;
  const int n0 = blockIdx.x * BN;

  float acc[TM][TN];
#pragma unroll
  for (int i = 0; i < TM; ++i)
#pragma unroll
    for (int j = 0; j < TN; ++j) acc[i][j] = 0.f;

  const int a_row = (tid * 4) / BK;
  const int a_col = (tid * 4) % BK;

  for (int k0 = 0; k0 < K; k0 += BK) {
    {
      int gm = m0 + a_row, gk = k0 + a_col;
      float4 v = make_float4(0.f, 0.f, 0.f, 0.f);
      if (gm < M) {
        if (gk + 3 < K) {
          v = *reinterpret_cast<const float4*>(A + (size_t)gm * lda + gk);
        } else {
          float tmp[4];
#pragma unroll
          for (int q = 0; q < 4; ++q)
            tmp[q] = (gk + q < K) ? A[(size_t)gm * lda + gk + q] : 0.f;
          v = make_float4(tmp[0], tmp[1], tmp[2], tmp[3]);
        }
      }
      As[a_col + 0][a_row] = v.x;
      As[a_col + 1][a_row] = v.y;
      As[a_col + 2][a_row] = v.z;
      As[a_col + 3][a_row] = v.w;
    }
    {
      int gn = n0 + a_row, gk = k0 + a_col;
      float4 v = make_float4(0.f, 0.f, 0.f, 0.f);
      if (gn < N) {
        if (gk + 3 < K) {
          v = *reinterpret_cast<const float4*>(W + (size_t)gn * ldw + gk);
        } else {
          float tmp[4];
#pragma unroll
          for (int q = 0; q < 4; ++q)
            tmp[q] = (gk + q < K) ? W[(size_t)gn * ldw + gk + q] : 0.f;
          v = make_float4(tmp[0], tmp[1], tmp[2], tmp[3]);
        }
      }
      Bs[a_col + 0][a_row] = v.x;
      Bs[a_col + 1][a_row] = v.y;
      Bs[a_col + 2][a_row] = v.z;
      Bs[a_col + 3][a_row] = v.w;
    }
    __syncthreads();
#pragma unroll
    for (int kk = 0; kk < BK; ++kk) {
      float a[TM], bb[TN];
#pragma unroll
      for (int i = 0; i < TM; i += 4)
        *reinterpret_cast<float4*>(&a[i]) =
            *reinterpret_cast<const float4*>(&As[kk][ty * TM + i]);
#pragma unroll
      for (int j = 0; j < TN; j += 4)
        *reinterpret_cast<float4*>(&bb[j]) =
            *reinterpret_cast<const float4*>(&Bs[kk][tx * TN + j]);
#pragma unroll
      for (int i = 0; i < TM; ++i)
#pragma unroll
        for (int j = 0; j < TN; ++j) acc[i][j] = fmaf(a[i], bb[j], acc[i][j]);
    }
    __syncthreads();
  }

#pragma unroll
  for (int i = 0; i < TM; ++i) {
    int m = m0 + ty * TM + i;
    if (m >= M) continue;
#pragma unroll
    for (int j = 0; j < TN; ++j) {
      int n = n0 + tx * TN + j;
      if (n >= N) continue;
      float v = acc[i][j];
      if (bias) v += bias[n];
      if (EPI == EPI_SOFTPLUS) {
        v = softplus_f(v);
      } else if (aux) {
        v += aux[(size_t)m * ldaux + n];
      }
      C[(size_t)m * ldc + n] = v;
    }
  }
}

// ---------------------------------------------------------------------------
// Point embeds
// ---------------------------------------------------------------------------
__global__ void anchor_embed_kernel(const float* __restrict__ mash,
                                    float* __restrict__ aemb) {
  int row = blockIdx.x;  // 0..1599
  int lane = threadIdx.x;
  if (lane >= 54) return;
  const float PI = 3.14159265358979323846f;
  float e;
  if (lane < 48) {
    int j = (lane < 24) ? lane : lane - 24;
    int d = j >> 2, f = j & 3;  // nf = 4
    float v = mash[row * 31 + d] * (PI * (float)(1 << f));
    e = (lane < 24) ? sinf(v) : cosf(v);
  } else {
    e = mash[row * 31 + (lane - 48)];
  }
  aemb[row * 54 + lane] = e;
}

// bf16 out [16384][64], cols 51..63 zero
__global__ void point_embed_q_kernel(const float* __restrict__ qry,
                                     unsigned short* __restrict__ qep) {
  int row = blockIdx.x;
  int lane = threadIdx.x;  // 64 lanes = 64 cols
  const float PI = 3.14159265358979323846f;
  float e = 0.f;
  if (lane < 48) {
    int j = (lane < 24) ? lane : lane - 24;
    int d = j >> 3, f = j & 7;  // nf = 8
    float v = qry[row * 3 + d] * (PI * (float)(1 << f));
    e = (lane < 24) ? sinf(v) : cosf(v);
  } else if (lane < 51) {
    e = qry[row * 3 + (lane - 48)];
  }
  qep[(size_t)row * 64 + lane] = f2bf(e);
}

__global__ void copy_tail_kernel(const float* __restrict__ mash,
                                 float* __restrict__ x) {
  int idx = blockIdx.x * 256 + threadIdx.x;
  if (idx >= 1600 * 25) return;
  int row = idx / 25, j = idx % 25;
  x[row * 400 + 375 + j] = mash[row * 31 + 6 + j];
}

// ---------------------------------------------------------------------------
// Norms -> bf16 padded [rows][416]
// ---------------------------------------------------------------------------
__global__ void rmsnorm_bf16_kernel(const float* __restrict__ x,
                                    const float* __restrict__ w,
                                    unsigned short* __restrict__ out) {
  int row = blockIdx.x;
  int lane = threadIdx.x;
  float ss = 0.f;
  float vals[7];
  int nv = 0;
  for (int c = lane; c < 400; c += 64) {
    float v = x[(size_t)row * 400 + c];
    vals[nv++] = v;
    ss += v * v;
  }
#pragma unroll
  for (int off = 1; off < 64; off <<= 1) ss += __shfl_xor(ss, off);
  float r = rsqrtf(ss * (1.f / 400.f) + 1e-5f);
  nv = 0;
  for (int c = lane; c < 416; c += 64) {
    unsigned short o = 0;
    if (c < 400) o = f2bf(vals[nv++] * r * w[c]);
    out[(size_t)row * 416 + c] = o;
  }
}

__global__ void layernorm_bf16_kernel(const float* __restrict__ x,
                                      const float* __restrict__ w,
                                      const float* __restrict__ b,
                                      unsigned short* __restrict__ out) {
  int row = blockIdx.x;
  int lane = threadIdx.x;
  float s = 0.f, s2 = 0.f;
  float vals[7];
  int nv = 0;
  for (int c = lane; c < 400; c += 64) {
    float v = x[(size_t)row * 400 + c];
    vals[nv++] = v;
    s += v;
    s2 += v * v;
  }
#pragma unroll
  for (int off = 1; off < 64; off <<= 1) {
    s += __shfl_xor(s, off);
    s2 += __shfl_xor(s2, off);
  }
  float mu = s * (1.f / 400.f);
  float var = s2 * (1.f / 400.f) - mu * mu;
  float r = rsqrtf(var + 1e-5f);
  nv = 0;
  for (int c = lane; c < 416; c += 64) {
    unsigned short o = 0;
    if (c < 400) o = f2bf((vals[nv++] - mu) * r * w[c] + b[c]);
    out[(size_t)row * 416 + c] = o;
  }
}

// ---------------------------------------------------------------------------
// Mamba pieces
// ---------------------------------------------------------------------------
__global__ void conv_silu_kernel(const float* __restrict__ uz,
                                 const float* __restrict__ cw,
                                 const float* __restrict__ cb,
                                 unsigned short* __restrict__ ucb,
                                 float* __restrict__ uc32) {
  int idx = blockIdx.x * 256 + threadIdx.x;
  if (idx >= 1600 * 800) return;
  int c = idx % 800;
  int row = idx / 800;
  int l = row % 400;
  int b = row / 400;
  float acc = cb[c];
  float w0 = cw[c * 4 + 0], w1 = cw[c * 4 + 1], w2 = cw[c * 4 + 2], w3 = cw[c * 4 + 3];
  const float* ub = uz + (size_t)b * 400 * 1600 + c;
  if (l >= 3) acc += ub[(size_t)(l - 3) * 1600] * w0;
  if (l >= 2) acc += ub[(size_t)(l - 2) * 1600] * w1;
  if (l >= 1) acc += ub[(size_t)(l - 1) * 1600] * w2;
  acc += ub[(size_t)l * 1600] * w3;
  float v = silu_f(acc);
  uc32[idx] = v;
  ucb[(size_t)row * 800 + c] = f2bf(v);
}

// 4 lanes per (b,d) channel, each owning 4 of the 16 states.
__global__ void scan_kernel(const float* __restrict__ uc,
                            const float* __restrict__ dt,
                            const float* __restrict__ dbc,
                            const float* __restrict__ A_log,
                            const float* __restrict__ Dp,
                            float* __restrict__ y) {
  int t = blockIdx.x * 256 + threadIdx.x;
  if (t >= 12800) return;
  int g = t & 3;
  int bd = t >> 2;
  int b = bd / 800;
  int d = bd - b * 800;
  float A0 = -__expf(A_log[d * 16 + g * 4 + 0]);
  float A1 = -__expf(A_log[d * 16 + g * 4 + 1]);
  float A2 = -__expf(A_log[d * 16 + g * 4 + 2]);
  float A3 = -__expf(A_log[d * 16 + g * 4 + 3]);
  float Dpd = Dp[d];
  float h0 = 0.f, h1 = 0.f, h2 = 0.f, h3 = 0.f;
  const int off = 25 + g * 4;
  for (int l = 0; l < 400; ++l) {
    size_t base = (size_t)(b * 400 + l);
    float dtv = dt[base * 800 + d];
    float uv = uc[base * 800 + d];
    float du = dtv * uv;
    const float* bc = dbc + base * 57;
    float B0 = bc[off + 0], B1 = bc[off + 1], B2 = bc[off + 2], B3 = bc[off + 3];
    float C0 = bc[off + 16], C1 = bc[off + 17], C2 = bc[off + 18], C3 = bc[off + 19];
    h0 = __expf(dtv * A0) * h0 + du * B0;
    h1 = __expf(dtv * A1) * h1 + du * B1;
    h2 = __expf(dtv * A2) * h2 + du * B2;
    h3 = __expf(dtv * A3) * h3 + du * B3;
    float yv = h0 * C0 + h1 * C1 + h2 * C2 + h3 * C3;
    yv += __shfl_xor(yv, 1);
    yv += __shfl_xor(yv, 2);
    if (g == 0) y[base * 800 + d] = yv + uv * Dpd;
  }
}

__global__ void gate_kernel(const float* __restrict__ y,
                            const float* __restrict__ uz,
                            unsigned short* __restrict__ gbuf) {
  int idx = blockIdx.x * 256 + threadIdx.x;
  if (idx >= 1600 * 800) return;
  int row = idx / 800, c = idx % 800;
  float z = uz[(size_t)row * 1600 + 800 + c];
  gbuf[(size_t)row * 800 + c] = f2bf(y[idx] * silu_f(z));
}

// ---------------------------------------------------------------------------
// Cross-attention: one block = 32 q-rows of a 2048-row chunk, one head.
// qh/oh: bf16 [2048][3200] (chunk base), kvb: bf16 [400][6400] (one batch).
// ---------------------------------------------------------------------------
__global__ __launch_bounds__(256) void attn_kernel(const unsigned short* __restrict__ qh,
                                                   const unsigned short* __restrict__ kvb,
                                                   unsigned short* __restrict__ oh) {
  __shared__ float qs[32][400];
  __shared__ float ss[32][400];
  __shared__ float ks[400][8];
  __shared__ float ls[32];
  const int tid = threadIdx.x;
  const int h = blockIdx.y;
  const int hoff = h * 400;
  const int row0 = blockIdx.x * 32;

  for (int idx = tid; idx < 32 * 400; idx += 256) {
    int r = idx / 400, c = idx % 400;
    qs[r][c] = bf2f(qh[(size_t)(row0 + r) * 3200 + hoff + c]);
  }
  __syncthreads();

  const int tx = tid & 15, ty = tid >> 4;
  const int r0 = ty * 2, r1 = ty * 2 + 1;

  float s0[25], s1[25];
#pragma unroll
  for (int ci = 0; ci < 25; ++ci) { s0[ci] = 0.f; s1[ci] = 0.f; }

  // Phase A: scores = q @ k^T
  for (int k0 = 0; k0 < 400; k0 += 8) {
    for (int idx = tid; idx < 400 * 8; idx += 256) {
      int j = idx >> 3, c = idx & 7;
      ks[j][c] = bf2f(kvb[(size_t)j * 6400 + hoff + k0 + c]);
    }
    __syncthreads();
#pragma unroll
    for (int kq = 0; kq < 8; kq += 4) {
      float4 qa0 = *reinterpret_cast<const float4*>(&qs[r0][k0 + kq]);
      float4 qa1 = *reinterpret_cast<const float4*>(&qs[r1][k0 + kq]);
#pragma unroll
      for (int ci = 0; ci < 25; ++ci) {
        float4 kb = *reinterpret_cast<const float4*>(&ks[tx + 16 * ci][kq]);
        s0[ci] += qa0.x * kb.x + qa0.y * kb.y + qa0.z * kb.z + qa0.w * kb.w;
        s1[ci] += qa1.x * kb.x + qa1.y * kb.y + qa1.z * kb.z + qa1.w * kb.w;
      }
    }
    __syncthreads();
  }

  const float scale = 0.05f;  // 400^-0.5
  float m0v = -1e30f, m1v = -1e30f;
#pragma unroll
  for (int ci = 0; ci < 25; ++ci) {
    m0v = fmaxf(m0v, s0[ci]);
    m1v = fmaxf(m1v, s1[ci]);
  }
#pragma unroll
  for (int off = 1; off < 16; off <<= 1) {
    m0v = fmaxf(m0v, __shfl_xor(m0v, off));
    m1v = fmaxf(m1v, __shfl_xor(m1v, off));
  }
  float l0 = 0.f, l1 = 0.f;
#pragma unroll
  for (int ci = 0; ci < 25; ++ci) {
    float p0 = __expf(scale * (s0[ci] - m0v));
    float p1 = __expf(scale * (s1[ci] - m1v));
    s0[ci] = p0;
    s1[ci] = p1;
    l0 += p0;
    l1 += p1;
  }
#pragma unroll
  for (int off = 1; off < 16; off <<= 1) {
    l0 += __shfl_xor(l0, off);
    l1 += __shfl_xor(l1, off);
  }
#pragma unroll
  for (int ci = 0; ci < 25; ++ci) {
    ss[r0][tx + 16 * ci] = s0[ci];
    ss[r1][tx + 16 * ci] = s1[ci];
  }
  if (tx == 0) {
    ls[r0] = 1.f / l0;
    ls[r1] = 1.f / l1;
  }

  float o0[25], o1[25];
#pragma unroll
  for (int ci = 0; ci < 25; ++ci) { o0[ci] = 0.f; o1[ci] = 0.f; }

  float* vs = &ks[0][0];  // reuse as [8][400]
  for (int j0 = 0; j0 < 400; j0 += 8) {
    __syncthreads();
    for (int idx = tid; idx < 8 * 400; idx += 256) {
      int j = idx / 400, c = idx % 400;
      vs[j * 400 + c] = bf2f(kvb[(size_t)(j0 + j) * 6400 + 3200 + hoff + c]);
    }
    __syncthreads();
    float p0[8], p1[8];
    *reinterpret_cast<float4*>(&p0[0]) = *reinterpret_cast<const float4*>(&ss[r0][j0]);
    *reinterpret_cast<float4*>(&p0[4]) = *reinterpret_cast<const float4*>(&ss[r0][j0 + 4]);
    *reinterpret_cast<float4*>(&p1[0]) = *reinterpret_cast<const float4*>(&ss[r1][j0]);
    *reinterpret_cast<float4*>(&p1[4]) = *reinterpret_cast<const float4*>(&ss[r1][j0 + 4]);
#pragma unroll
    for (int j = 0; j < 8; ++j) {
#pragma unroll
      for (int ci = 0; ci < 25; ++ci) {
        float v = vs[j * 400 + tx + 16 * ci];
        o0[ci] = fmaf(p0[j], v, o0[ci]);
        o1[ci] = fmaf(p1[j], v, o1[ci]);
      }
    }
  }
  __syncthreads();
#pragma unroll
  for (int ci = 0; ci < 25; ++ci) {
    ss[r0][tx + 16 * ci] = o0[ci];
    ss[r1][tx + 16 * ci] = o1[ci];
  }
  __syncthreads();
  for (int idx = tid; idx < 32 * 400; idx += 256) {
    int r = idx / 400, c = idx % 400;
    oh[(size_t)(row0 + r) * 3200 + hoff + c] = f2bf(ss[r][c] * ls[r]);
  }
}

// ---------------------------------------------------------------------------
// misc
// ---------------------------------------------------------------------------
__global__ void head_kernel(const float* __restrict__ lat,
                            const float* __restrict__ hw,
                            const float* __restrict__ hb,
                            float* __restrict__ out) {
  int row = blockIdx.x * 4 + (threadIdx.x >> 6);
  int lane = threadIdx.x & 63;
  float s = 0.f;
  for (int c = lane; c < 400; c += 64) s += lat[(size_t)row * 400 + c] * hw[c];
#pragma unroll
  for (int off = 1; off < 64; off <<= 1) s += __shfl_xor(s, off);
  if (lane == 0) out[row] = s + hb[0];
}

// ---------------------------------------------------------------------------
// host
// ---------------------------------------------------------------------------
static inline int cdiv(int a, int b) { return (a + b - 1) / b; }
static inline int cvtblocks(long long elems) { return (int)((elems / 8 + 255) / 256); }

extern "C" void kernel_launch(void* const* d_in, const int* in_sizes, int n_in,
                              void* d_out, int out_size, void* d_ws, size_t ws_size,
                              hipStream_t stream) {
  (void)in_sizes; (void)n_in; (void)out_size;

  const float* mash     = (const float*)d_in[0];
  const float* qry      = (const float*)d_in[1];
  const float* anchor_w = (const float*)d_in[2];
  const float* anchor_b = (const float*)d_in[3];
  const float* point_w  = (const float*)d_in[4];
  const float* point_b  = (const float*)d_in[5];
  const float* norm_w   = (const float*)d_in[6];
  const float* in_w     = (const float*)d_in[7];
  const float* conv_w   = (const float*)d_in[8];
  const float* conv_b   = (const float*)d_in[9];
  const float* xproj_w  = (const float*)d_in[10];
  const float* dt_w     = (const float*)d_in[11];
  const float* dt_b     = (const float*)d_in[12];
  const float* A_log    = (const float*)d_in[13];
  const float* Dp       = (const float*)d_in[14];
  const float* out_w    = (const float*)d_in[15];
  const float* ln_q_w   = (const float*)d_in[16];
  const float* ln_q_b   = (const float*)d_in[17];
  const float* ln_c_w   = (const float*)d_in[18];
  const float* ln_c_b   = (const float*)d_in[19];
  const float* to_q_w   = (const float*)d_in[20];
  const float* to_kv_w  = (const float*)d_in[21];
  const float* to_out_w = (const float*)d_in[22];
  const float* to_out_b = (const float*)d_in[23];
  const float* ff_ln_w  = (const float*)d_in[24];
  const float* ff_ln_b  = (const float*)d_in[25];
  const float* ff_w1    = (const float*)d_in[26];
  const float* ff_b1    = (const float*)d_in[27];
  const float* ff_w2    = (const float*)d_in[28];
  const float* ff_b2    = (const float*)d_in[29];
  const float* head_w   = (const float*)d_in[30];
  const float* head_b   = (const float*)d_in[31];

  // ---- workspace layout (float offsets; bf16 regions count elems/2) ----
  const size_t WI   = 0;           // in_w bf16 [24][1664][416] = 8,306,688 fl
  const size_t WX   = 8306688;     // xproj bf16 [24][128][800] = 1,228,800
  const size_t WO   = 9535488;     // out_w bf16 [24][512][800] = 4,915,200
  const size_t WKV  = 14450688;    // to_kv bf16 [6400][416]    = 1,331,200
  const size_t WP   = 15781888;    // point bf16 [512][64]      = 16,384
  const size_t WQ   = 15798272;    // to_q bf16 [3200][416]     = 665,600
  const size_t WTO  = 16463872;    // to_out bf16 [512][3200]   = 819,200
  const size_t WF1  = 17283072;    // ff_w1 bf16 [3264][416]    = 678,912
  const size_t WF2  = 17961984;    // ff_w2 bf16 [512][1600]    = 409,600
  const size_t XOFF = 18371584;    // X fp32 [1600][400]        = 640,000
  const size_t LATO = 19011584;    // LAT fp32 [16384][400]     = 6,553,600
  const size_t P    = 25565184;    // phase pool
  // mamba pool:
  const size_t XNB  = P + 0;        // bf16 [1664][416]  = 346,112
  const size_t UZ   = P + 346112;   // f32 [1600][1600]  = 2,560,000
  const size_t UCB  = P + 2906112;  // bf16 [1664][800]  = 665,600
  const size_t UC32 = P + 3571712;  // f32 [1600][800]   = 1,280,000
  const size_t DTO  = P + 4851712;  // f32 [1600][800]   = 1,280,000
  const size_t DBC  = P + 6131712;  // f32 [1600][57]    = 91,200
  const size_t YB   = P + 6222912;  // f32 [1600][800]   = 1,280,000
  const size_t GB   = P + 7502912;  // bf16 [1664][800]  = 665,600
  const size_t AEMB = P + 8168512;  // f32 [1600][54]    = 86,400
  // attn pool:
  const size_t A0   = P + 0;         // KV bf16 [1600][6400] = 5,120,000
  const size_t A1   = P + 5120000;   // QN bf16 [16384][416] = 3,407,872
  const size_t A2   = P + 8527872;   // XNctx / QEP / QH_c   = 3,276,800
  const size_t A3   = P + 11804672;  // QEMB_c f32 / OH_c    = 3,276,800
  // ff pool:
  const size_t LNL  = P + 0;        // bf16 [16384][416] = 3,407,872
  const size_t FFA  = P + 3407872;  // f32 [4096][1600]  = 6,553,600
  const size_t FFG  = P + 9961472;  // bf16 [4096][1600] = 3,276,800
  const size_t TOTAL = P + 15081472;  // 40,646,656 floats = 162.6 MB

  if (ws_size < TOTAL * sizeof(float)) return;

  float* ws = (float*)d_ws;
  float* X    = ws + XOFF;
  float* LAT  = ws + LATO;
  unsigned short* pWI  = (unsigned short*)(ws + WI);
  unsigned short* pWX  = (unsigned short*)(ws + WX);
  unsigned short* pWO  = (unsigned short*)(ws + WO);
  unsigned short* pWKV = (unsigned short*)(ws + WKV);
  unsigned short* pWP  = (unsigned short*)(ws + WP);
  unsigned short* pWQ  = (unsigned short*)(ws + WQ);
  unsigned short* pWTO = (unsigned short*)(ws + WTO);
  unsigned short* pWF1 = (unsigned short*)(ws + WF1);
  unsigned short* pWF2 = (unsigned short*)(ws + WF2);

  // ---- weight conversion (every call; ws is re-poisoned by harness) ----
  cvt_w_kernel<<<cvtblocks(24LL*1664*416), 256, 0, stream>>>(in_w,    pWI, 24, 1600, 400, 1664, 416);
  cvt_w_kernel<<<cvtblocks(24LL*128*800),  256, 0, stream>>>(xproj_w, pWX, 24, 57,   800, 128,  800);
  cvt_w_kernel<<<cvtblocks(24LL*512*800),  256, 0, stream>>>(out_w,   pWO, 24, 400,  800, 512,  800);
  cvt_w_kernel<<<cvtblocks(6400LL*416),    256, 0, stream>>>(to_kv_w, pWKV, 1, 6400, 400, 6400, 416);
  cvt_w_kernel<<<cvtblocks(512LL*64),      256, 0, stream>>>(point_w, pWP,  1, 400,  51,  512,  64);
  cvt_w_kernel<<<cvtblocks(3200LL*416),    256, 0, stream>>>(to_q_w,  pWQ,  1, 3200, 400, 3200, 416);
  cvt_w_kernel<<<cvtblocks(512LL*3200),    256, 0, stream>>>(to_out_w,pWTO, 1, 400, 3200, 512,  3200);
  cvt_w_kernel<<<cvtblocks(3264LL*416),    256, 0, stream>>>(ff_w1,   pWF1, 1, 3200, 400, 3264, 416);
  cvt_w_kernel<<<cvtblocks(512LL*1600),    256, 0, stream>>>(ff_w2,   pWF2, 1, 400, 1600, 512,  1600);

  // ---- anchor embed -> X [1600][400] (fp32 path, tiny K) ----
  anchor_embed_kernel<<<1600, 64, 0, stream>>>(mash, ws + AEMB);
  gemm_k<64, 64, 16, 4, 4, EPI_NONE><<<dim3(6, 25), 256, 0, stream>>>(
      ws + AEMB, 54, anchor_w, 54, anchor_b, nullptr, 0, X, 400, 1600, 375, 54);
  copy_tail_kernel<<<cdiv(1600 * 25, 256), 256, 0, stream>>>(mash, X);

  // ---- 24 mamba blocks ----
  for (int L = 0; L < 24; ++L) {
    rmsnorm_bf16_kernel<<<1600, 64, 0, stream>>>(X, norm_w + (size_t)L * 400,
                                                 (unsigned short*)(ws + XNB));
    gemm_bf16_k<EPI_NONE, 0><<<dim3(13, 13), 256, 0, stream>>>(
        (unsigned short*)(ws + XNB), 416, pWI + (size_t)L * 1664 * 416, 416,
        nullptr, nullptr, 0, ws + UZ, 1600, 1600, 1600, 416);
    conv_silu_kernel<<<cdiv(1600 * 800, 256), 256, 0, stream>>>(
        ws + UZ, conv_w + (size_t)L * 3200, conv_b + (size_t)L * 800,
        (unsigned short*)(ws + UCB), ws + UC32);
    gemm_bf16_k<EPI_NONE, 0><<<dim3(1, 13), 256, 0, stream>>>(
        (unsigned short*)(ws + UCB), 800, pWX + (size_t)L * 128 * 800, 800,
        nullptr, nullptr, 0, ws + DBC, 57, 1600, 57, 800);
    gemm_k<64, 64, 16, 4, 4, EPI_SOFTPLUS><<<dim3(13, 25), 256, 0, stream>>>(
        ws + DBC, 57, dt_w + (size_t)L * 800 * 25, 25, dt_b + (size_t)L * 800,
        nullptr, 0, ws + DTO, 800, 1600, 800, 25);
    scan_kernel<<<50, 256, 0, stream>>>(ws + UC32, ws + DTO, ws + DBC,
                                        A_log + (size_t)L * 12800,
                                        Dp + (size_t)L * 800, ws + YB);
    gate_kernel<<<cdiv(1600 * 800, 256), 256, 0, stream>>>(
        ws + YB, ws + UZ, (unsigned short*)(ws + GB));
    gemm_bf16_k<EPI_RES, 0><<<dim3(4, 13), 256, 0, stream>>>(
        (unsigned short*)(ws + GB), 800, pWO + (size_t)L * 512 * 800, 800,
        nullptr, X, 400, X, 400, 1600, 400, 800);
  }

  // ---- context LN + KV projection (bf16 out) ----
  layernorm_bf16_kernel<<<1600, 64, 0, stream>>>(X, ln_c_w, ln_c_b,
                                                 (unsigned short*)(ws + A2));
  gemm_bf16_k<EPI_NONE, 1><<<dim3(50, 13), 256, 0, stream>>>(
      (unsigned short*)(ws + A2), 416, pWKV, 416, nullptr, nullptr, 0,
      (unsigned short*)(ws + A0), 6400, 1600, 6400, 416);

  // ---- query embed (bf16) -> per-chunk GEMM + LN -> QN bf16 ----
  point_embed_q_kernel<<<16384, 64, 0, stream>>>(qry, (unsigned short*)(ws + A2));
  for (int c = 0; c < 8; ++c) {
    gemm_bf16_k<EPI_NONE, 0><<<dim3(4, 16), 256, 0, stream>>>(
        (unsigned short*)(ws + A2) + (size_t)c * 2048 * 64, 64, pWP, 64, point_b,
        nullptr, 0, ws + A3, 400, 2048, 400, 64);
    layernorm_bf16_kernel<<<2048, 64, 0, stream>>>(
        ws + A3, ln_q_w, ln_q_b,
        (unsigned short*)(ws + A1) + (size_t)c * 2048 * 416);
  }

  // ---- attention per 2048-row chunk: to_q -> attn -> to_out ----
  for (int c = 0; c < 8; ++c) {
    unsigned short* QHc = (unsigned short*)(ws + A2);
    unsigned short* OHc = (unsigned short*)(ws + A3);
    gemm_bf16_k<EPI_NONE, 1><<<dim3(25, 16), 256, 0, stream>>>(
        (unsigned short*)(ws + A1) + (size_t)c * 2048 * 416, 416, pWQ, 416,
        nullptr, nullptr, 0, QHc, 3200, 2048, 3200, 416);
    attn_kernel<<<dim3(64, 8), 256, 0, stream>>>(
        QHc, (unsigned short*)(ws + A0) + (size_t)(c >> 1) * 400 * 6400, OHc);
    gemm_bf16_k<EPI_NONE, 0><<<dim3(4, 16), 256, 0, stream>>>(
        OHc, 3200, pWTO, 3200, to_out_b, nullptr, 0,
        LAT + (size_t)c * 2048 * 400, 400, 2048, 400, 3200);
  }

  // ---- GEGLU FF (per batch) ----
  layernorm_bf16_kernel<<<16384, 64, 0, stream>>>(LAT, ff_ln_w, ff_ln_b,
                                                  (unsigned short*)(ws + LNL));
  for (int bb = 0; bb < 4; ++bb) {
    unsigned short* lnb = (unsigned short*)(ws + LNL) + (size_t)bb * 4096 * 416;
    float* latb = LAT + (size_t)bb * 4096 * 400;
    gemm_bf16_k<EPI_NONE, 0><<<dim3(13, 32), 256, 0, stream>>>(
        lnb, 416, pWF1, 416, ff_b1, nullptr, 0, ws + FFA, 1600, 4096, 1600, 416);
    gemm_bf16_k<EPI_GEGLU, 1><<<dim3(13, 32), 256, 0, stream>>>(
        lnb, 416, pWF1 + (size_t)1600 * 416, 416, ff_b1 + 1600, ws + FFA, 1600,
        (unsigned short*)(ws + FFG), 1600, 4096, 1600, 416);
    gemm_bf16_k<EPI_RES, 0><<<dim3(4, 32), 256, 0, stream>>>(
        (unsigned short*)(ws + FFG), 1600, pWF2, 1600, ff_b2, latb, 400, latb,
        400, 4096, 400, 1600);
  }

  // ---- head ----
  head_kernel<<<4096, 256, 0, stream>>>(LAT, head_w, head_b, (float*)d_out);
}

// Round 5
// 7994.995 us; speedup vs baseline: 2.4185x; 1.9194x over previous
//
#include <hip/hip_runtime.h>

// ---------------------------------------------------------------------------
// MashDecoder forward. Round 3 (resubmit x2): MFMA attention, fused scan+gate.
// B=4, NA=400, NQ=4096, D_HIDDEN=400, D_INNER=800, D_STATE=16, DT_RANK=25
// ---------------------------------------------------------------------------

#define EPI_NONE 0
#define EPI_SOFTPLUS 1
#define EPI_RES 2
#define EPI_GEGLU 3

typedef short bf16x8 __attribute__((ext_vector_type(8)));
typedef float f32x4 __attribute__((ext_vector_type(4)));

static __device__ __forceinline__ float silu_f(float x) {
  return x / (1.f + __expf(-x));
}
static __device__ __forceinline__ float softplus_f(float x) {
  return fmaxf(x, 0.f) + log1pf(__expf(-fabsf(x)));
}
static __device__ __forceinline__ float gelu_f(float x) {
  const float c = 0.7978845608028654f;  // sqrt(2/pi)
  return 0.5f * x * (1.f + tanhf(c * (x + 0.044715f * x * x * x)));
}
static __device__ __forceinline__ unsigned short f2bf(float f) {
  union { float f; unsigned int u; } v; v.f = f;
  unsigned int r = v.u + 0x7FFFu + ((v.u >> 16) & 1u);  // RNE
  return (unsigned short)(r >> 16);
}
static __device__ __forceinline__ float bf2f(unsigned short h) {
  union { unsigned int u; float f; } v; v.u = ((unsigned int)h) << 16;
  return v.f;
}

// ---------------------------------------------------------------------------
// Weight converts
// ---------------------------------------------------------------------------
// generic: src fp32 [L][R][C] -> dst bf16 [L][Rp][Cp], zero pad tail rows/cols
__global__ void cvt_w_kernel(const float* __restrict__ src, unsigned short* __restrict__ dst,
                             int Lr, int R, int C, int Rp, int Cp) {
  size_t i8 = ((size_t)blockIdx.x * 256 + threadIdx.x) * 8;
  size_t total = (size_t)Lr * Rp * Cp;
  if (i8 >= total) return;
  int cp = (int)(i8 % Cp);
  size_t rl = i8 / Cp;
  int r = (int)(rl % Rp);
  int l = (int)(rl / Rp);
  const float* s = src + ((size_t)l * R + r) * C + cp;
  bf16x8 o;
#pragma unroll
  for (int q = 0; q < 8; ++q) {
    float v = (r < R && (cp + q) < C) ? s[q] : 0.f;
    o[q] = (short)f2bf(v);
  }
  *reinterpret_cast<bf16x8*>(dst + i8) = o;
}

// per-head row pad: src [HB*400][400] -> dst [HB*416][416], zero pads
__global__ void cvt_headrow_k(const float* __restrict__ src, unsigned short* __restrict__ dst,
                              int HB) {
  size_t i8 = ((size_t)blockIdx.x * 256 + threadIdx.x) * 8;
  size_t total = (size_t)HB * 416 * 416;
  if (i8 >= total) return;
  int c = (int)(i8 % 416);
  int n = (int)(i8 / 416);
  int head = n / 416, r = n % 416;
  const float* s = src + ((size_t)(head * 400 + r)) * 400 + c;
  bf16x8 o;
#pragma unroll
  for (int q = 0; q < 8; ++q) {
    float v = (r < 400 && (c + q) < 400) ? s[q] : 0.f;
    o[q] = (short)f2bf(v);
  }
  *reinterpret_cast<bf16x8*>(dst + i8) = o;
}

// per-head col pad: src [400][HB*400] -> dst [512][HB*416], zero pads
__global__ void cvt_colhead_k(const float* __restrict__ src, unsigned short* __restrict__ dst,
                              int HB) {
  size_t i8 = ((size_t)blockIdx.x * 256 + threadIdx.x) * 8;
  size_t total = (size_t)512 * HB * 416;
  if (i8 >= total) return;
  int cp = (int)(i8 % ((size_t)HB * 416));
  int r = (int)(i8 / ((size_t)HB * 416));
  int head = cp / 416, cc = cp % 416;
  bf16x8 o;
#pragma unroll
  for (int q = 0; q < 8; ++q) {
    int c = cc + q;
    float v = (r < 400 && c < 400) ? src[(size_t)r * (HB * 400) + head * 400 + c] : 0.f;
    o[q] = (short)f2bf(v);
  }
  *reinterpret_cast<bf16x8*>(dst + i8) = o;
}

// ---------------------------------------------------------------------------
// bf16 MFMA GEMM, z-batched: C[z][M,N] = epi(A[z][M,K] @ W[z][N,K]^T + bias)
// ---------------------------------------------------------------------------
template <int EPI, int OUTBF>
__global__ __launch_bounds__(256) void gemm_bf16_k(
    const unsigned short* __restrict__ A, int lda, long long zsA,
    const unsigned short* __restrict__ W, int ldw, long long zsW,
    const float* __restrict__ bias,
    const float* __restrict__ aux, int ldaux,
    void* __restrict__ Cout, int ldc, long long zsC,
    int M, int N, int K) {
  __shared__ unsigned short As[128 * 32];
  __shared__ unsigned short Bs[128 * 32];
  const int tid = threadIdx.x;
  const int lane = tid & 63;
  const int wid = tid >> 6;
  const int wr = wid >> 1, wc = wid & 1;
  const int m0 = blockIdx.y * 128, n0 = blockIdx.x * 128;
  const long long z = blockIdx.z;
  A += z * zsA;
  W += z * zsW;

  f32x4 acc[4][4];
#pragma unroll
  for (int i = 0; i < 4; ++i)
#pragma unroll
    for (int j = 0; j < 4; ++j) acc[i][j] = (f32x4){0.f, 0.f, 0.f, 0.f};

  const int i0 = tid;
  const int i1 = tid + 256;
  const unsigned short* gA0 = A + (size_t)(m0 + (i0 >> 2)) * lda + ((i0 & 3) << 3);
  const unsigned short* gA1 = A + (size_t)(m0 + (i1 >> 2)) * lda + ((i1 & 3) << 3);
  const unsigned short* gB0 = W + (size_t)(n0 + (i0 >> 2)) * ldw + ((i0 & 3) << 3);
  const unsigned short* gB1 = W + (size_t)(n0 + (i1 >> 2)) * ldw + ((i1 & 3) << 3);
  unsigned short* lA0 = &As[i0 * 8];
  unsigned short* lA1 = &As[i1 * 8];
  unsigned short* lB0 = &Bs[i0 * 8];
  unsigned short* lB1 = &Bs[i1 * 8];

  const int fr = lane & 15, fq = lane >> 4;
  const int arow = wr * 64 + fr;
  const int brow = wc * 64 + fr;

  for (int k0 = 0; k0 < K; k0 += 32) {
    __builtin_amdgcn_global_load_lds(
        (const __attribute__((address_space(1))) unsigned int*)(gA0 + k0),
        (__attribute__((address_space(3))) unsigned int*)lA0, 16, 0, 0);
    __builtin_amdgcn_global_load_lds(
        (const __attribute__((address_space(1))) unsigned int*)(gA1 + k0),
        (__attribute__((address_space(3))) unsigned int*)lA1, 16, 0, 0);
    __builtin_amdgcn_global_load_lds(
        (const __attribute__((address_space(1))) unsigned int*)(gB0 + k0),
        (__attribute__((address_space(3))) unsigned int*)lB0, 16, 0, 0);
    __builtin_amdgcn_global_load_lds(
        (const __attribute__((address_space(1))) unsigned int*)(gB1 + k0),
        (__attribute__((address_space(3))) unsigned int*)lB1, 16, 0, 0);
    __syncthreads();
    bf16x8 av[4], bv[4];
#pragma unroll
    for (int mi = 0; mi < 4; ++mi)
      av[mi] = *reinterpret_cast<const bf16x8*>(&As[(arow + mi * 16) * 32 + fq * 8]);
#pragma unroll
    for (int ni = 0; ni < 4; ++ni)
      bv[ni] = *reinterpret_cast<const bf16x8*>(&Bs[(brow + ni * 16) * 32 + fq * 8]);
#pragma unroll
    for (int mi = 0; mi < 4; ++mi)
#pragma unroll
      for (int ni = 0; ni < 4; ++ni)
        acc[mi][ni] =
            __builtin_amdgcn_mfma_f32_16x16x32_bf16(av[mi], bv[ni], acc[mi][ni], 0, 0, 0);
    __syncthreads();
  }

  float* Cf = (float*)Cout + z * zsC;
  unsigned short* Cb = (unsigned short*)Cout + z * zsC;
  const float* auxp = aux ? aux + z * zsC : aux;
#pragma unroll
  for (int mi = 0; mi < 4; ++mi) {
#pragma unroll
    for (int r = 0; r < 4; ++r) {
      int m = m0 + wr * 64 + mi * 16 + fq * 4 + r;
      if (m >= M) continue;
#pragma unroll
      for (int ni = 0; ni < 4; ++ni) {
        int n = n0 + wc * 64 + ni * 16 + fr;
        if (n >= N) continue;
        float v = acc[mi][ni][r];
        if (bias) v += bias[n];
        if (EPI == EPI_GEGLU) v = auxp[(size_t)m * ldaux + n] * gelu_f(v);
        else if (EPI == EPI_RES) v += auxp[(size_t)m * ldaux + n];
        if (OUTBF) Cb[(size_t)m * ldc + n] = f2bf(v);
        else Cf[(size_t)m * ldc + n] = v;
      }
    }
  }
}

// ---------------------------------------------------------------------------
// fp32 GEMM (tiny shapes: anchor embed K=54, dt-proj K=25)
// ---------------------------------------------------------------------------
template <int BM, int BN, int BK, int TM, int TN, int EPI>
__global__ __launch_bounds__(256) void gemm_k(
    const float* __restrict__ A, int lda,
    const float* __restrict__ W, int ldw,
    const float* __restrict__ bias,
    float* __restrict__ C, int ldc,
    int M, int N, int K) {
  __shared__ float As[BK][BM];
  __shared__ float Bs[BK][BN];
  const int tid = threadIdx.x;
  const int tx = tid % (BN / TN);
  const int ty = tid / (BN / TN);
  const int m0 = blockIdx.y * BM;
  const int n0 = blockIdx.x * BN;

  float acc[TM][TN];
#pragma unroll
  for (int i = 0; i < TM; ++i)
#pragma unroll
    for (int j = 0; j < TN; ++j) acc[i][j] = 0.f;

  const int a_row = (tid * 4) / BK;
  const int a_col = (tid * 4) % BK;

  for (int k0 = 0; k0 < K; k0 += BK) {
    {
      int gm = m0 + a_row, gk = k0 + a_col;
      float4 v = make_float4(0.f, 0.f, 0.f, 0.f);
      if (gm < M) {
        if (gk + 3 < K) {
          v = *reinterpret_cast<const float4*>(A + (size_t)gm * lda + gk);
        } else {
          float tmp[4];
#pragma unroll
          for (int q = 0; q < 4; ++q)
            tmp[q] = (gk + q < K) ? A[(size_t)gm * lda + gk + q] : 0.f;
          v = make_float4(tmp[0], tmp[1], tmp[2], tmp[3]);
        }
      }
      As[a_col + 0][a_row] = v.x;
      As[a_col + 1][a_row] = v.y;
      As[a_col + 2][a_row] = v.z;
      As[a_col + 3][a_row] = v.w;
    }
    {
      int gn = n0 + a_row, gk = k0 + a_col;
      float4 v = make_float4(0.f, 0.f, 0.f, 0.f);
      if (gn < N) {
        if (gk + 3 < K) {
          v = *reinterpret_cast<const float4*>(W + (size_t)gn * ldw + gk);
        } else {
          float tmp[4];
#pragma unroll
          for (int q = 0; q < 4; ++q)
            tmp[q] = (gk + q < K) ? W[(size_t)gn * ldw + gk + q] : 0.f;
          v = make_float4(tmp[0], tmp[1], tmp[2], tmp[3]);
        }
      }
      Bs[a_col + 0][a_row] = v.x;
      Bs[a_col + 1][a_row] = v.y;
      Bs[a_col + 2][a_row] = v.z;
      Bs[a_col + 3][a_row] = v.w;
    }
    __syncthreads();
#pragma unroll
    for (int kk = 0; kk < BK; ++kk) {
      float a[TM], bb[TN];
#pragma unroll
      for (int i = 0; i < TM; i += 4)
        *reinterpret_cast<float4*>(&a[i]) =
            *reinterpret_cast<const float4*>(&As[kk][ty * TM + i]);
#pragma unroll
      for (int j = 0; j < TN; j += 4)
        *reinterpret_cast<float4*>(&bb[j]) =
            *reinterpret_cast<const float4*>(&Bs[kk][tx * TN + j]);
#pragma unroll
      for (int i = 0; i < TM; ++i)
#pragma unroll
        for (int j = 0; j < TN; ++j) acc[i][j] = fmaf(a[i], bb[j], acc[i][j]);
    }
    __syncthreads();
  }

#pragma unroll
  for (int i = 0; i < TM; ++i) {
    int m = m0 + ty * TM + i;
    if (m >= M) continue;
#pragma unroll
    for (int j = 0; j < TN; ++j) {
      int n = n0 + tx * TN + j;
      if (n >= N) continue;
      float v = acc[i][j];
      if (bias) v += bias[n];
      if (EPI == EPI_SOFTPLUS) v = softplus_f(v);
      C[(size_t)m * ldc + n] = v;
    }
  }
}

// ---------------------------------------------------------------------------
// Point embeds
// ---------------------------------------------------------------------------
__global__ void anchor_embed_kernel(const float* __restrict__ mash,
                                    float* __restrict__ aemb) {
  int row = blockIdx.x;
  int lane = threadIdx.x;
  if (lane >= 54) return;
  const float PI = 3.14159265358979323846f;
  float e;
  if (lane < 48) {
    int j = (lane < 24) ? lane : lane - 24;
    int d = j >> 2, f = j & 3;  // nf = 4
    float v = mash[row * 31 + d] * (PI * (float)(1 << f));
    e = (lane < 24) ? sinf(v) : cosf(v);
  } else {
    e = mash[row * 31 + (lane - 48)];
  }
  aemb[row * 54 + lane] = e;
}

__global__ void point_embed_q_kernel(const float* __restrict__ qry,
                                     unsigned short* __restrict__ qep) {
  int row = blockIdx.x;
  int lane = threadIdx.x;
  const float PI = 3.14159265358979323846f;
  float e = 0.f;
  if (lane < 48) {
    int j = (lane < 24) ? lane : lane - 24;
    int d = j >> 3, f = j & 7;  // nf = 8
    float v = qry[row * 3 + d] * (PI * (float)(1 << f));
    e = (lane < 24) ? sinf(v) : cosf(v);
  } else if (lane < 51) {
    e = qry[row * 3 + (lane - 48)];
  }
  qep[(size_t)row * 64 + lane] = f2bf(e);
}

__global__ void copy_tail_kernel(const float* __restrict__ mash,
                                 float* __restrict__ x) {
  int idx = blockIdx.x * 256 + threadIdx.x;
  if (idx >= 1600 * 25) return;
  int row = idx / 25, j = idx % 25;
  x[row * 400 + 375 + j] = mash[row * 31 + 6 + j];
}

// ---------------------------------------------------------------------------
// Norms -> bf16 padded [rows][416]
// ---------------------------------------------------------------------------
__global__ void rmsnorm_bf16_kernel(const float* __restrict__ x,
                                    const float* __restrict__ w,
                                    unsigned short* __restrict__ out) {
  int row = blockIdx.x;
  int lane = threadIdx.x;
  float ss = 0.f;
  float vals[7];
  int nv = 0;
  for (int c = lane; c < 400; c += 64) {
    float v = x[(size_t)row * 400 + c];
    vals[nv++] = v;
    ss += v * v;
  }
#pragma unroll
  for (int off = 1; off < 64; off <<= 1) ss += __shfl_xor(ss, off);
  float r = rsqrtf(ss * (1.f / 400.f) + 1e-5f);
  nv = 0;
  for (int c = lane; c < 416; c += 64) {
    unsigned short o = 0;
    if (c < 400) o = f2bf(vals[nv++] * r * w[c]);
    out[(size_t)row * 416 + c] = o;
  }
}

__global__ void layernorm_bf16_kernel(const float* __restrict__ x,
                                      const float* __restrict__ w,
                                      const float* __restrict__ b,
                                      unsigned short* __restrict__ out) {
  int row = blockIdx.x;
  int lane = threadIdx.x;
  float s = 0.f, s2 = 0.f;
  float vals[7];
  int nv = 0;
  for (int c = lane; c < 400; c += 64) {
    float v = x[(size_t)row * 400 + c];
    vals[nv++] = v;
    s += v;
    s2 += v * v;
  }
#pragma unroll
  for (int off = 1; off < 64; off <<= 1) {
    s += __shfl_xor(s, off);
    s2 += __shfl_xor(s2, off);
  }
  float mu = s * (1.f / 400.f);
  float var = s2 * (1.f / 400.f) - mu * mu;
  float r = rsqrtf(var + 1e-5f);
  nv = 0;
  for (int c = lane; c < 416; c += 64) {
    unsigned short o = 0;
    if (c < 400) o = f2bf((vals[nv++] - mu) * r * w[c] + b[c]);
    out[(size_t)row * 416 + c] = o;
  }
}

// ---------------------------------------------------------------------------
// Mamba pieces
// ---------------------------------------------------------------------------
__global__ void conv_silu_kernel(const float* __restrict__ uz,
                                 const float* __restrict__ cw,
                                 const float* __restrict__ cb,
                                 unsigned short* __restrict__ ucb,
                                 float* __restrict__ uc32) {
  int idx = blockIdx.x * 256 + threadIdx.x;
  if (idx >= 1600 * 800) return;
  int c = idx % 800;
  int row = idx / 800;
  int l = row % 400;
  int b = row / 400;
  float acc = cb[c];
  float w0 = cw[c * 4 + 0], w1 = cw[c * 4 + 1], w2 = cw[c * 4 + 2], w3 = cw[c * 4 + 3];
  const float* ub = uz + (size_t)b * 400 * 1600 + c;
  if (l >= 3) acc += ub[(size_t)(l - 3) * 1600] * w0;
  if (l >= 2) acc += ub[(size_t)(l - 2) * 1600] * w1;
  if (l >= 1) acc += ub[(size_t)(l - 1) * 1600] * w2;
  acc += ub[(size_t)l * 1600] * w3;
  float v = silu_f(acc);
  uc32[idx] = v;
  ucb[(size_t)row * 800 + c] = f2bf(v);
}

// 4 lanes per (b,d) channel; fused gate epilogue; 4-step pipelined loads.
__global__ void scan_kernel(const float* __restrict__ uc,
                            const float* __restrict__ dt,
                            const float* __restrict__ dbc,
                            const float* __restrict__ uz,
                            const float* __restrict__ A_log,
                            const float* __restrict__ Dp,
                            unsigned short* __restrict__ gb) {
  int t = blockIdx.x * 256 + threadIdx.x;
  if (t >= 12800) return;
  int g = t & 3;
  int bd = t >> 2;
  int b = bd / 800;
  int d = bd - b * 800;
  float A0 = -__expf(A_log[d * 16 + g * 4 + 0]);
  float A1 = -__expf(A_log[d * 16 + g * 4 + 1]);
  float A2 = -__expf(A_log[d * 16 + g * 4 + 2]);
  float A3 = -__expf(A_log[d * 16 + g * 4 + 3]);
  float Dpd = Dp[d];
  float h0 = 0.f, h1 = 0.f, h2 = 0.f, h3 = 0.f;
  const int off = 25 + g * 4;
  for (int l0 = 0; l0 < 400; l0 += 4) {
    float dtv[4], uv[4], zv[4], Bv[4][4], Cv[4][4];
#pragma unroll
    for (int q = 0; q < 4; ++q) {
      size_t base = (size_t)(b * 400 + l0 + q);
      dtv[q] = dt[base * 800 + d];
      uv[q] = uc[base * 800 + d];
      zv[q] = uz[base * 1600 + 800 + d];
      const float* bc = dbc + base * 57 + off;
#pragma unroll
      for (int s = 0; s < 4; ++s) {
        Bv[q][s] = bc[s];
        Cv[q][s] = bc[16 + s];
      }
    }
#pragma unroll
    for (int q = 0; q < 4; ++q) {
      float du = dtv[q] * uv[q];
      h0 = __expf(dtv[q] * A0) * h0 + du * Bv[q][0];
      h1 = __expf(dtv[q] * A1) * h1 + du * Bv[q][1];
      h2 = __expf(dtv[q] * A2) * h2 + du * Bv[q][2];
      h3 = __expf(dtv[q] * A3) * h3 + du * Bv[q][3];
      float yv = h0 * Cv[q][0] + h1 * Cv[q][1] + h2 * Cv[q][2] + h3 * Cv[q][3];
      yv += __shfl_xor(yv, 1);
      yv += __shfl_xor(yv, 2);
      if (g == 0) {
        size_t base = (size_t)(b * 400 + l0 + q);
        gb[base * 800 + d] = f2bf((yv + uv[q] * Dpd) * silu_f(zv[q]));
      }
    }
  }
}

// ---------------------------------------------------------------------------
// Softmax over 400 keys, in-place f32 S row -> bf16 P row (ld 416 f32 / 832 sh)
// ---------------------------------------------------------------------------
__global__ void softmax_k(float* S) {
  int row = blockIdx.x * 4 + (threadIdx.x >> 6);
  int lane = threadIdx.x & 63;
  float* sr = S + (size_t)row * 416;
  float v[7];
  float m = -1e30f;
#pragma unroll
  for (int i = 0; i < 7; ++i) {
    int c = lane + i * 64;
    v[i] = (c < 400) ? sr[c] : -1e30f;
    m = fmaxf(m, v[i]);
  }
#pragma unroll
  for (int off = 1; off < 64; off <<= 1) m = fmaxf(m, __shfl_xor(m, off));
  float sum = 0.f;
#pragma unroll
  for (int i = 0; i < 7; ++i) {
    int c = lane + i * 64;
    float p = (c < 400) ? __expf(0.05f * (v[i] - m)) : 0.f;
    v[i] = p;
    sum += p;
  }
#pragma unroll
  for (int off = 1; off < 64; off <<= 1) sum += __shfl_xor(sum, off);
  float inv = 1.f / sum;
  unsigned short* pr = (unsigned short*)sr;
#pragma unroll
  for (int i = 0; i < 7; ++i) {
    int c = lane + i * 64;
    if (c < 400) pr[c] = f2bf(v[i] * inv);
    else if (c < 416) pr[c] = 0;
  }
}

// ---------------------------------------------------------------------------
// V transpose: KVp V-half [b][j][h*416+d] -> VT [b][512 d][416 j], zeros pad.
// grid (13 j-tiles, 8 d-tiles, 4 b); one head per launch.
// ---------------------------------------------------------------------------
__global__ void vt_repack_k(const unsigned short* __restrict__ kvp,
                            unsigned short* __restrict__ vt, int h) {
  __shared__ unsigned short tbuf[32][66];
  int tid = threadIdx.x;
  int b = blockIdx.z;
  int j0 = blockIdx.x * 32, d0 = blockIdx.y * 64;
  for (int idx = tid; idx < 32 * 64; idx += 256) {
    int j = idx >> 6, dd = idx & 63;
    unsigned short val = 0;
    if (j0 + j < 400 && d0 + dd < 400)
      val = kvp[(size_t)(b * 400 + j0 + j) * 6656 + 3328 + h * 416 + d0 + dd];
    tbuf[j][dd] = val;
  }
  __syncthreads();
  for (int idx = tid; idx < 64 * 32; idx += 256) {
    int dd = idx >> 5, j = idx & 31;
    vt[(size_t)(b * 512 + d0 + dd) * 416 + j0 + j] = tbuf[j][dd];
  }
}

// ---------------------------------------------------------------------------
// head
// ---------------------------------------------------------------------------
__global__ void head_kernel(const float* __restrict__ lat,
                            const float* __restrict__ hw,
                            const float* __restrict__ hb,
                            float* __restrict__ out) {
  int row = blockIdx.x * 4 + (threadIdx.x >> 6);
  int lane = threadIdx.x & 63;
  float s = 0.f;
  for (int c = lane; c < 400; c += 64) s += lat[(size_t)row * 400 + c] * hw[c];
#pragma unroll
  for (int off = 1; off < 64; off <<= 1) s += __shfl_xor(s, off);
  if (lane == 0) out[row] = s + hb[0];
}

// ---------------------------------------------------------------------------
// host
// ---------------------------------------------------------------------------
static inline int cdiv(int a, int b) { return (a + b - 1) / b; }
static inline int cvtblocks(long long elems) { return (int)((elems / 8 + 255) / 256); }

extern "C" void kernel_launch(void* const* d_in, const int* in_sizes, int n_in,
                              void* d_out, int out_size, void* d_ws, size_t ws_size,
                              hipStream_t stream) {
  (void)in_sizes; (void)n_in; (void)out_size;

  const float* mash     = (const float*)d_in[0];
  const float* qry      = (const float*)d_in[1];
  const float* anchor_w = (const float*)d_in[2];
  const float* anchor_b = (const float*)d_in[3];
  const float* point_w  = (const float*)d_in[4];
  const float* point_b  = (const float*)d_in[5];
  const float* norm_w   = (const float*)d_in[6];
  const float* in_w     = (const float*)d_in[7];
  const float* conv_w   = (const float*)d_in[8];
  const float* conv_b   = (const float*)d_in[9];
  const float* xproj_w  = (const float*)d_in[10];
  const float* dt_w     = (const float*)d_in[11];
  const float* dt_b     = (const float*)d_in[12];
  const float* A_log    = (const float*)d_in[13];
  const float* Dp       = (const float*)d_in[14];
  const float* out_w    = (const float*)d_in[15];
  const float* ln_q_w   = (const float*)d_in[16];
  const float* ln_q_b   = (const float*)d_in[17];
  const float* ln_c_w   = (const float*)d_in[18];
  const float* ln_c_b   = (const float*)d_in[19];
  const float* to_q_w   = (const float*)d_in[20];
  const float* to_kv_w  = (const float*)d_in[21];
  const float* to_out_w = (const float*)d_in[22];
  const float* to_out_b = (const float*)d_in[23];
  const float* ff_ln_w  = (const float*)d_in[24];
  const float* ff_ln_b  = (const float*)d_in[25];
  const float* ff_w1    = (const float*)d_in[26];
  const float* ff_b1    = (const float*)d_in[27];
  const float* ff_w2    = (const float*)d_in[28];
  const float* ff_b2    = (const float*)d_in[29];
  const float* head_w   = (const float*)d_in[30];
  const float* head_b   = (const float*)d_in[31];

  // ---- workspace layout (float offsets) ----
  const size_t WI   = 0;           // in_w bf16 [24][1664][416]  = 8,306,688
  const size_t WX   = 8306688;     // xproj bf16 [24][128][800]  = 1,228,800
  const size_t WO   = 9535488;     // out_w bf16 [24][512][800]  = 4,915,200
  const size_t WKV  = 14450688;    // to_kv bf16 [6656][416]     = 1,384,448
  const size_t WP   = 15835136;    // point bf16 [512][64]       = 16,384
  const size_t WQ   = 15851520;    // to_q bf16 [3456][416]      = 718,848
  const size_t WTO  = 16570368;    // to_out bf16 [512][3328]    = 851,968
  const size_t WF1  = 17422336;    // ff_w1 bf16 [3264][416]     = 678,912
  const size_t WF2  = 18101248;    // ff_w2 bf16 [512][1600]     = 409,600
  const size_t XOFF = 18510848;    // X fp32 [1600][400]         = 640,000
  const size_t LATO = 19150848;    // LAT fp32 [16384][400]      = 6,553,600
  const size_t P    = 25704448;    // phase pool
  // region0 overlays (attn/FF phases):
  const size_t QEMB = 0;           // f32 [16384][400]  = 6,553,600
  const size_t SOFF = 0;           // f32 [16384][416]  = 6,815,744 (S / in-place P)
  const size_t CTX  = 6815744;     // bf16 [1664][416]  = 346,112
  const size_t QH   = 6815744;     // bf16 [16384][416] = 3,407,872 (also PV out)
  const size_t VT   = 10223616;    // bf16 [4][512][416] = 426,496
  const size_t QEP  = 10650112;    // bf16 [16384][64]  = 524,288
  const size_t FFA  = 0;           // f32 [4096][1600]  = 6,553,600 (FF phase)
  // pool (max of phases):
  const size_t XNB  = P + 0;        // bf16 [1664][416]  = 346,112
  const size_t UZ   = P + 346112;   // f32 [1600][1600]  = 2,560,000
  const size_t UCB  = P + 2906112;  // bf16 [1664][800]  = 665,600
  const size_t UC32 = P + 3571712;  // f32 [1600][800]   = 1,280,000
  const size_t DTO  = P + 4851712;  // f32 [1600][800]   = 1,280,000
  const size_t DBC  = P + 6131712;  // f32 [1600][57]    = 91,200
  const size_t GB   = P + 6222912;  // bf16 [1664][800]  = 665,600
  const size_t AEMB = P + 6888512;  // f32 [1600][54]    = 86,400
  const size_t QN   = P + 0;        // bf16 [16384][416] = 3,407,872 (attn)
  const size_t KVP  = P + 3407872;  // bf16 [1728][6656] = 5,750,784 (attn)
  const size_t LNL  = P + 0;        // bf16 [16384][416] = 3,407,872 (ff)
  const size_t FFG  = P + 3407872;  // bf16 [4096][1600] = 3,276,800 (ff)
  const size_t TOTAL = P + 9158656; // = 34,863,104 floats = 139.5 MB

  if (ws_size < TOTAL * sizeof(float)) return;

  float* ws = (float*)d_ws;
  float* X   = ws + XOFF;
  float* LAT = ws + LATO;
  unsigned short* pWI  = (unsigned short*)(ws + WI);
  unsigned short* pWX  = (unsigned short*)(ws + WX);
  unsigned short* pWO  = (unsigned short*)(ws + WO);
  unsigned short* pWKV = (unsigned short*)(ws + WKV);
  unsigned short* pWP  = (unsigned short*)(ws + WP);
  unsigned short* pWQ  = (unsigned short*)(ws + WQ);
  unsigned short* pWTO = (unsigned short*)(ws + WTO);
  unsigned short* pWF1 = (unsigned short*)(ws + WF1);
  unsigned short* pWF2 = (unsigned short*)(ws + WF2);

  // ---- weight conversion ----
  cvt_w_kernel<<<cvtblocks(24LL*1664*416), 256, 0, stream>>>(in_w,   pWI, 24, 1600, 400, 1664, 416);
  cvt_w_kernel<<<cvtblocks(24LL*128*800),  256, 0, stream>>>(xproj_w,pWX, 24, 57,   800, 128,  800);
  cvt_w_kernel<<<cvtblocks(24LL*512*800),  256, 0, stream>>>(out_w,  pWO, 24, 400,  800, 512,  800);
  cvt_headrow_k<<<cvtblocks(16LL*416*416), 256, 0, stream>>>(to_kv_w, pWKV, 16);
  cvt_w_kernel<<<cvtblocks(512LL*64),      256, 0, stream>>>(point_w, pWP, 1, 400, 51, 512, 64);
  cvt_headrow_k<<<cvtblocks(8LL*416*416),  256, 0, stream>>>(to_q_w, pWQ, 8);
  cvt_colhead_k<<<cvtblocks(512LL*8*416),  256, 0, stream>>>(to_out_w, pWTO, 8);
  cvt_w_kernel<<<cvtblocks(3264LL*416),    256, 0, stream>>>(ff_w1, pWF1, 1, 3200, 400, 3264, 416);
  cvt_w_kernel<<<cvtblocks(512LL*1600),    256, 0, stream>>>(ff_w2, pWF2, 1, 400, 1600, 512, 1600);

  // ---- anchor embed -> X ----
  anchor_embed_kernel<<<1600, 64, 0, stream>>>(mash, ws + AEMB);
  gemm_k<64, 64, 16, 4, 4, EPI_NONE><<<dim3(6, 25), 256, 0, stream>>>(
      ws + AEMB, 54, anchor_w, 54, anchor_b, X, 400, 1600, 375, 54);
  copy_tail_kernel<<<cdiv(1600 * 25, 256), 256, 0, stream>>>(mash, X);

  // ---- 24 mamba blocks ----
  for (int L = 0; L < 24; ++L) {
    rmsnorm_bf16_kernel<<<1600, 64, 0, stream>>>(X, norm_w + (size_t)L * 400,
                                                 (unsigned short*)(ws + XNB));
    gemm_bf16_k<EPI_NONE, 0><<<dim3(13, 13), 256, 0, stream>>>(
        (unsigned short*)(ws + XNB), 416, 0, pWI + (size_t)L * 1664 * 416, 416, 0,
        nullptr, nullptr, 0, ws + UZ, 1600, 0, 1600, 1600, 416);
    conv_silu_kernel<<<cdiv(1600 * 800, 256), 256, 0, stream>>>(
        ws + UZ, conv_w + (size_t)L * 3200, conv_b + (size_t)L * 800,
        (unsigned short*)(ws + UCB), ws + UC32);
    gemm_bf16_k<EPI_NONE, 0><<<dim3(1, 13), 256, 0, stream>>>(
        (unsigned short*)(ws + UCB), 800, 0, pWX + (size_t)L * 128 * 800, 800, 0,
        nullptr, nullptr, 0, ws + DBC, 57, 0, 1600, 57, 800);
    gemm_k<64, 64, 16, 4, 4, EPI_SOFTPLUS><<<dim3(13, 25), 256, 0, stream>>>(
        ws + DBC, 57, dt_w + (size_t)L * 800 * 25, 25, dt_b + (size_t)L * 800,
        ws + DTO, 800, 1600, 800, 25);
    scan_kernel<<<50, 256, 0, stream>>>(ws + UC32, ws + DTO, ws + DBC, ws + UZ,
                                        A_log + (size_t)L * 12800,
                                        Dp + (size_t)L * 800,
                                        (unsigned short*)(ws + GB));
    gemm_bf16_k<EPI_RES, 0><<<dim3(4, 13), 256, 0, stream>>>(
        (unsigned short*)(ws + GB), 800, 0, pWO + (size_t)L * 512 * 800, 800, 0,
        nullptr, X, 400, X, 400, 0, 1600, 400, 800);
  }

  // ---- context LN -> KV projection (head-padded bf16) ----
  layernorm_bf16_kernel<<<1600, 64, 0, stream>>>(X, ln_c_w, ln_c_b,
                                                 (unsigned short*)(ws + CTX));
  gemm_bf16_k<EPI_NONE, 1><<<dim3(52, 13), 256, 0, stream>>>(
      (unsigned short*)(ws + CTX), 416, 0, pWKV, 416, 0, nullptr, nullptr, 0,
      (unsigned short*)(ws + KVP), 6656, 0, 1600, 6656, 416);

  // ---- query embed -> point GEMM -> LN -> QN ----
  point_embed_q_kernel<<<16384, 64, 0, stream>>>(qry, (unsigned short*)(ws + QEP));
  gemm_bf16_k<EPI_NONE, 0><<<dim3(4, 128), 256, 0, stream>>>(
      (unsigned short*)(ws + QEP), 64, 0, pWP, 64, 0, point_b, nullptr, 0,
      ws + QEMB, 400, 0, 16384, 400, 64);
  layernorm_bf16_kernel<<<16384, 64, 0, stream>>>(ws + QEMB, ln_q_w, ln_q_b,
                                                  (unsigned short*)(ws + QN));

  // ---- attention: per head, batched-z over 4 batches ----
  for (int h = 0; h < 8; ++h) {
    vt_repack_k<<<dim3(13, 8, 4), 256, 0, stream>>>(
        (unsigned short*)(ws + KVP), (unsigned short*)(ws + VT), h);
    // Qh = QN @ Wq_h^T  [16384][416]
    gemm_bf16_k<EPI_NONE, 1><<<dim3(4, 128), 256, 0, stream>>>(
        (unsigned short*)(ws + QN), 416, 0, pWQ + (size_t)h * 416 * 416, 416, 0,
        nullptr, nullptr, 0, (unsigned short*)(ws + QH), 416, 0, 16384, 416, 416);
    // S = Qh @ K_bh^T  (f32), z = batch
    gemm_bf16_k<EPI_NONE, 0><<<dim3(4, 32, 4), 256, 0, stream>>>(
        (unsigned short*)(ws + QH), 416, 4096LL * 416,
        (unsigned short*)(ws + KVP) + (size_t)h * 416, 6656, 400LL * 6656,
        nullptr, nullptr, 0, ws + SOFF, 416, 4096LL * 416, 4096, 400, 416);
    // softmax rows, in-place bf16 P
    softmax_k<<<4096, 256, 0, stream>>>(ws + SOFF);
    // O = P @ V^T -> QH (bf16), z = batch
    gemm_bf16_k<EPI_NONE, 1><<<dim3(4, 32, 4), 256, 0, stream>>>(
        (unsigned short*)(ws + SOFF), 832, 4096LL * 832,
        (unsigned short*)(ws + VT), 416, 512LL * 416,
        nullptr, nullptr, 0, (unsigned short*)(ws + QH), 416, 4096LL * 416,
        4096, 400, 416);
    // LAT (+)= O @ Wto_h^T
    if (h == 0) {
      gemm_bf16_k<EPI_NONE, 0><<<dim3(4, 128), 256, 0, stream>>>(
          (unsigned short*)(ws + QH), 416, 0, pWTO + (size_t)h * 416, 3328, 0,
          to_out_b, nullptr, 0, LAT, 400, 0, 16384, 400, 416);
    } else {
      gemm_bf16_k<EPI_RES, 0><<<dim3(4, 128), 256, 0, stream>>>(
          (unsigned short*)(ws + QH), 416, 0, pWTO + (size_t)h * 416, 3328, 0,
          nullptr, LAT, 400, LAT, 400, 0, 16384, 400, 416);
    }
  }

  // ---- GEGLU FF (per batch) ----
  layernorm_bf16_kernel<<<16384, 64, 0, stream>>>(LAT, ff_ln_w, ff_ln_b,
                                                  (unsigned short*)(ws + LNL));
  for (int bb = 0; bb < 4; ++bb) {
    unsigned short* lnb = (unsigned short*)(ws + LNL) + (size_t)bb * 4096 * 416;
    float* latb = LAT + (size_t)bb * 4096 * 400;
    gemm_bf16_k<EPI_NONE, 0><<<dim3(13, 32), 256, 0, stream>>>(
        lnb, 416, 0, pWF1, 416, 0, ff_b1, nullptr, 0, ws + FFA, 1600, 0,
        4096, 1600, 416);
    gemm_bf16_k<EPI_GEGLU, 1><<<dim3(13, 32), 256, 0, stream>>>(
        lnb, 416, 0, pWF1 + (size_t)1600 * 416, 416, 0, ff_b1 + 1600,
        ws + FFA, 1600, (unsigned short*)(ws + FFG), 1600, 0, 4096, 1600, 416);
    gemm_bf16_k<EPI_RES, 0><<<dim3(4, 32), 256, 0, stream>>>(
        (unsigned short*)(ws + FFG), 1600, 0, pWF2, 1600, 0, ff_b2, latb, 400,
        latb, 400, 0, 4096, 400, 1600);
  }

  // ---- head ----
  head_kernel<<<4096, 256, 0, stream>>>(LAT, head_w, head_b, (float*)d_out);
}